// Round 16
// baseline (1084.208 us; speedup 1.0000x reference)
//
#include <hip/hip_runtime.h>

#define NN   30000
#define NE   480000
#define NR   7
#define NSEG (NN*NR)
#define DH   512
#define DIN  21
#define EPSB 1e-5f
#define BK   32
#define KSEG 3584          // 7*512 gathered columns (self handled from hbf)

typedef __attribute__((ext_vector_type(8))) short bf16x8;
typedef __attribute__((ext_vector_type(8))) unsigned short u16x8;
typedef __attribute__((ext_vector_type(4))) float f32x4;
typedef unsigned short ushortT;

static inline size_t align256(size_t x){ return (x + 255) & ~(size_t)255; }

__device__ inline float bf2f(ushortT u){
    unsigned int i = ((unsigned int)u) << 16; float f; __builtin_memcpy(&f, &i, 4); return f;
}
__device__ inline ushortT f2bf(float f){
    unsigned int i; __builtin_memcpy(&i, &f, 4);
    unsigned int r = i + 0x7FFFu + ((i >> 16) & 1u);
    return (ushortT)(r >> 16);
}

__device__ inline void load_lds16(const ushortT* g, ushortT* l){
    __builtin_amdgcn_global_load_lds((const __attribute__((address_space(1))) unsigned int*)g,
                                     (__attribute__((address_space(3))) unsigned int*)l,
                                     16, 0, 0);
}

// ---------------- CSR build (counting sort by seg = dst*7+rel) ----------------

__global__ void hist_k(const int* __restrict__ dst, const int* __restrict__ rel,
                       int* __restrict__ counts){
    int e = blockIdx.x*256 + threadIdx.x;
    if (e < NE) atomicAdd(&counts[dst[e]*NR + rel[e]], 1);
}

__global__ void scan1_k(const int* __restrict__ counts, int* __restrict__ bsum){
    __shared__ int sd[256];
    int t = threadIdx.x;
    int base = blockIdx.x*1024 + t*4;
    int s = 0;
#pragma unroll
    for (int i = 0; i < 4; i++){ int idx = base + i; if (idx < NSEG) s += counts[idx]; }
    sd[t] = s; __syncthreads();
    for (int off = 128; off > 0; off >>= 1){
        if (t < off) sd[t] += sd[t+off];
        __syncthreads();
    }
    if (t == 0) bsum[blockIdx.x] = sd[0];
}

__global__ void scan2_k(int* __restrict__ bsum, int nb, int* __restrict__ seg_start){
    __shared__ int sd[256];
    int t = threadIdx.x;
    int v = (t < nb) ? bsum[t] : 0;
    sd[t] = v; __syncthreads();
    for (int off = 1; off < 256; off <<= 1){
        int x = sd[t];
        if (t >= off) x += sd[t-off];
        __syncthreads();
        sd[t] = x; __syncthreads();
    }
    if (t < nb) bsum[t] = (t == 0) ? 0 : sd[t-1];
    if (t == 0) seg_start[NSEG] = NE;
}

__global__ void scan3_k(const int* __restrict__ counts, const int* __restrict__ bsum,
                        int* __restrict__ seg_start){
    __shared__ int sd[256];
    int t = threadIdx.x;
    int base = blockIdx.x*1024 + t*4;
    int v[4]; int s = 0;
#pragma unroll
    for (int i = 0; i < 4; i++){ int idx = base + i; v[i] = (idx < NSEG) ? counts[idx] : 0; s += v[i]; }
    sd[t] = s; __syncthreads();
    for (int off = 1; off < 256; off <<= 1){
        int x = sd[t];
        if (t >= off) x += sd[t-off];
        __syncthreads();
        sd[t] = x; __syncthreads();
    }
    int excl = sd[t] - s + bsum[blockIdx.x];
#pragma unroll
    for (int i = 0; i < 4; i++){
        int idx = base + i;
        if (idx < NSEG){ seg_start[idx] = excl; excl += v[i]; }
    }
}

__global__ void scatter_k(const int* __restrict__ src, const int* __restrict__ dst,
                          const int* __restrict__ rel, const int* __restrict__ seg_start,
                          int* __restrict__ cursor, int* __restrict__ src_sorted){
    int e = blockIdx.x*256 + threadIdx.x;
    if (e < NE){
        int s = dst[e]*NR + rel[e];
        int pos = seg_start[s] + atomicAdd(&cursor[s], 1);
        src_sorted[pos] = src[e];
    }
}

// ---------------- layer 0: segment sum d=21, Kp=192 (147 upd | 21 self | 24 pad) ----------------

__global__ void segsum21b_k(const float* __restrict__ x0,
                            const int* __restrict__ seg_start, const int* __restrict__ src_sorted,
                            ushortT* __restrict__ Acat0){
    int n = blockIdx.x;
    int t = threadIdx.x;   // 64
    ushortT* arow = Acat0 + (long)n*192;
    if (t < DIN){
        int sb = n*NR;
        int e0 = seg_start[sb];
#pragma unroll
        for (int r = 0; r < NR; r++){
            int e1 = seg_start[sb + r + 1];
            float a = 0.f;
            for (int e = e0; e < e1; e++) a += x0[(long)src_sorted[e]*DIN + t];
            e0 = e1;
            arow[r*DIN + t] = f2bf(a);
        }
        arow[7*DIN + t] = f2bf(x0[(long)n*DIN + t]);
    }
    if (t >= 40) arow[168 + (t - 40)] = 0;   // zero pad cols 168..191
}

// ---------------- segsum (layers 1,2): one WAVE per node → Acat[*,3584], grid-stride --------

__device__ inline void segsum_body(const ushortT* __restrict__ hbf,
                                   const int* __restrict__ seg_start,
                                   const int* __restrict__ src_sorted,
                                   ushortT* __restrict__ Acat,
                                   int wid, int c0, int lane){
    const int n = c0 + wid;
    const int co = lane*8;

    int sb[8];
#pragma unroll
    for (int i = 0; i < 8; i++) sb[i] = seg_start[n*NR + i];

    ushortT* arow = Acat + (long)wid*KSEG + co;
#pragma unroll
    for (int r = 0; r < NR; r++){
        float a[8];
#pragma unroll
        for (int j = 0; j < 8; j++) a[j] = 0.f;
        int e = sb[r], e1 = sb[r+1];
        for (; e + 3 < e1; e += 4){
            u16x8 v0 = *reinterpret_cast<const u16x8*>(hbf + (long)src_sorted[e  ]*DH + co);
            u16x8 v1 = *reinterpret_cast<const u16x8*>(hbf + (long)src_sorted[e+1]*DH + co);
            u16x8 v2 = *reinterpret_cast<const u16x8*>(hbf + (long)src_sorted[e+2]*DH + co);
            u16x8 v3 = *reinterpret_cast<const u16x8*>(hbf + (long)src_sorted[e+3]*DH + co);
#pragma unroll
            for (int j = 0; j < 8; j++)
                a[j] += (bf2f((ushortT)v0[j]) + bf2f((ushortT)v1[j]))
                      + (bf2f((ushortT)v2[j]) + bf2f((ushortT)v3[j]));
        }
        for (; e < e1; e++){
            u16x8 v = *reinterpret_cast<const u16x8*>(hbf + (long)src_sorted[e]*DH + co);
#pragma unroll
            for (int j = 0; j < 8; j++) a[j] += bf2f((ushortT)v[j]);
        }
        u16x8 o;
#pragma unroll
        for (int j = 0; j < 8; j++) o[j] = f2bf(a[j]);
        *reinterpret_cast<u16x8*>(arow + r*DH) = o;
    }
}

__global__ __launch_bounds__(256)
void segsum_wave_k(const ushortT* __restrict__ hbf,
                   const int* __restrict__ seg_start, const int* __restrict__ src_sorted,
                   ushortT* __restrict__ Acat, int c0, int cn){
    const int lane = threadIdx.x & 63;
    const int gwave = (blockIdx.x*256 + threadIdx.x) >> 6;
    const int nwaves = (gridDim.x*256) >> 6;
    for (int wid = gwave; wid < cn; wid += nwaves)
        segsum_body(hbf, seg_start, src_sorted, Acat, wid, c0, lane);
}

// ---------------- weight concat + bf16 convert: Wcat[512][Kp] ----------------

__global__ void convw_k(const float* __restrict__ lw, const float* __restrict__ sw,
                        int d, int Kp, ushortT* __restrict__ Wc){
    int i = blockIdx.x*256 + threadIdx.x;
    if (i < DH*Kp){
        int n = i / Kp, k = i % Kp;
        float v;
        if (k < 7*d)      v = lw[(long)n*7*d + k];
        else if (k < 8*d) v = sw[(long)n*d + (k - 7*d)];
        else              v = 0.f;
        Wc[i] = f2bf(v);
    }
}

// ---------------- MFMA GEMM (128x128, R12 config) — FULL-M single dispatch ----------------
// 940 blocks ≈ 3.7/CU, 48 KB LDS → 3 resident blocks/CU = 12 waves/CU (m97 residency).
// T2 swizzle both sides (0 bank conflicts), 3-deep pipeline, counted vmcnt(4), raw barrier,
// bijective XCD panel swizzle (panel col-tiles co-XCD → A working set L3-bounded).
// C written fp32 directly into d_out slice (ldc=3*DH), fused col-stats.

__global__ __launch_bounds__(256)
void gemm_mfma_k(const ushortT* __restrict__ A, int lda, int ntA,
                 const ushortT* __restrict__ hbase, int M,
                 const ushortT* __restrict__ W, int ldw,
                 const float* __restrict__ b1, const float* __restrict__ b2,
                 float* __restrict__ C, int ldc, int nt, float* __restrict__ sums){
    __shared__ ushortT As[3][128*BK];   // 24 KB
    __shared__ ushortT Bs[3][128*BK];   // 24 KB
    const int t = threadIdx.x;

    // bijective XCD swizzle (m204); panel = l>>2, col-tile = l&3
    const int nwg = gridDim.x;
    int q = nwg >> 3, rmd = nwg & 7;
    int xcd = blockIdx.x & 7, slot = blockIdx.x >> 3;
    int l = xcd*q + min(xcd, rmd) + slot;
    const int bm = (l >> 2)*128;
    const int bn = (l & 3)*128;

    const int w    = t >> 6;
    const int lane = t & 63;

    int f0 = w*128 + lane, f1 = f0 + 64;
    // T2: swizzled k-chunk for the global source of LDS unit f
    const int ac0 = (((f0 & 3) ^ ((f0 >> 3) & 3)))*8;
    const int ac1 = (((f1 & 3) ^ ((f1 >> 3) & 3)))*8;
    const int ar0 = min(bm + (f0 >> 2), M-1);
    const int ar1 = min(bm + (f1 >> 2), M-1);
    const int br0 = bn + (f0 >> 2), br1 = bn + (f1 >> 2);
    const int d0 = (w*128 +  0)*8;
    const int d1 = (w*128 + 64)*8;

    f32x4 acc[4][4];
#pragma unroll
    for (int m = 0; m < 4; m++)
#pragma unroll
        for (int n = 0; n < 4; n++) acc[m][n] = (f32x4){0.f,0.f,0.f,0.f};

    const int wm = w >> 1, wn = w & 1;
    const int r = lane & 15, hi = lane >> 4;
    const int xr = (r >> 1) & 3;            // T2 read-side XOR
    const int ko = (hi ^ xr)*8;

    auto stage = [&](int kt, int b){
        const ushortT* p0;
        const ushortT* p1;
        if (kt < ntA){
            p0 = A + (long)ar0*lda + kt*BK + ac0;
            p1 = A + (long)ar1*lda + kt*BK + ac1;
        } else {
            int k0 = (kt - ntA)*BK;
            p0 = hbase + (long)ar0*DH + k0 + ac0;
            p1 = hbase + (long)ar1*DH + k0 + ac1;
        }
        load_lds16(p0, &As[b][d0]);
        load_lds16(p1, &As[b][d1]);
        load_lds16(W + (long)br0*ldw + kt*BK + ac0, &Bs[b][d0]);
        load_lds16(W + (long)br1*ldw + kt*BK + ac1, &Bs[b][d1]);
    };

    stage(0, 0);
    if (nt > 1) stage(1, 1);

    for (int kt = 0; kt < nt; ++kt){
        if (kt + 1 < nt) asm volatile("s_waitcnt vmcnt(4)" ::: "memory");
        else             asm volatile("s_waitcnt vmcnt(0)" ::: "memory");
        __builtin_amdgcn_s_barrier();
        __builtin_amdgcn_sched_barrier(0);
        if (kt + 2 < nt) stage(kt + 2, (kt + 2) % 3);
        const int buf = kt % 3;
        bf16x8 af[4], bfr[4];
#pragma unroll
        for (int m = 0; m < 4; m++)
            af[m] = *reinterpret_cast<const bf16x8*>(&As[buf][(wm*64 + m*16 + r)*BK + ko]);
#pragma unroll
        for (int n = 0; n < 4; n++)
            bfr[n] = *reinterpret_cast<const bf16x8*>(&Bs[buf][(wn*64 + n*16 + r)*BK + ko]);
#pragma unroll
        for (int m = 0; m < 4; m++)
#pragma unroll
            for (int n = 0; n < 4; n++)
                acc[m][n] = __builtin_amdgcn_mfma_f32_16x16x32_bf16(af[m], bfr[n], acc[m][n], 0, 0, 0);
    }

    // epilogue: bias + fp32 store (strided into d_out) + fused column stats
#pragma unroll
    for (int n = 0; n < 4; n++){
        int col = bn + wn*64 + n*16 + r;
        float bb = b1[col] + b2[col];
        float s = 0.f, s2 = 0.f;
#pragma unroll
        for (int m = 0; m < 4; m++){
            int row = bm + wm*64 + m*16 + hi*4;
#pragma unroll
            for (int q2 = 0; q2 < 4; q2++){
                if (row + q2 < M){
                    float v = acc[m][n][q2] + bb;
                    C[(long)(row + q2)*ldc + col] = v;
                    s += v; s2 = fmaf(v, v, s2);
                }
            }
        }
        s  += __shfl_xor(s, 16);  s  += __shfl_xor(s, 32);
        s2 += __shfl_xor(s2, 16); s2 += __shfl_xor(s2, 32);
        if (hi == 0){
            atomicAdd(&sums[col], s);
            atomicAdd(&sums[DH + col], s2);
        }
    }
}

// ---------------- BatchNorm passes (fp32 in d_out, in place) ----------------

__global__ void finalize_k(const float* __restrict__ sums, const float* __restrict__ g,
                           const float* __restrict__ b, float* __restrict__ ac){
    int c = blockIdx.x*256 + threadIdx.x;
    if (c < DH){
        float mu  = sums[c] * (1.f/NN);
        float var = sums[DH + c] * (1.f/NN) - mu*mu;
        var = fmaxf(var, 0.f);
        float a = g[c] * rsqrtf(var + EPSB);
        ac[c]      = a;
        ac[DH + c] = fmaf(-mu, a, b[c]);
    }
}

__global__ void bnrelu_k(float* __restrict__ o, int M, const float* __restrict__ ac,
                         float* __restrict__ sums2){
    int col = blockIdx.x*256 + threadIdx.x;
    int r0 = blockIdx.y*128;
    int r1 = min(r0 + 128, M);
    float a = ac[col], c = ac[DH + col];
    float s = 0.f, s2 = 0.f;
    for (int r = r0; r < r1; r++){
        long idx = (long)r*(3*DH) + col;
        float y = fmaxf(fmaf(a, o[idx], c), 0.f);
        o[idx] = y;
        s += y; s2 = fmaf(y, y, s2);
    }
    atomicAdd(&sums2[col], s);
    atomicAdd(&sums2[DH + col], s2);
}

__global__ void bn2write_k(float* __restrict__ o, const float* __restrict__ ac,
                           ushortT* __restrict__ hbf){
    long i = (long)blockIdx.x*256 + threadIdx.x;
    if (i < (long)NN*DH){
        int r = (int)(i >> 9);
        int c = (int)(i & 511);
        long idx = (long)r*(3*DH) + c;
        float h = fmaf(ac[c], o[idx], ac[DH + c]);
        o[idx] = h;
        hbf[i] = f2bf(h);
    }
}

// ---------------- driver ----------------

extern "C" void kernel_launch(void* const* d_in, const int* in_sizes, int n_in,
                              void* d_out, int out_size, void* d_ws, size_t ws_size,
                              hipStream_t stream){
    const float* x0  = (const float*)d_in[0];
    const int*   src = (const int*)d_in[1];
    const int*   dst = (const int*)d_in[2];
    const int*   rel = (const int*)d_in[3];
    const float* lin_w[3]  = {(const float*)d_in[4],  (const float*)d_in[12], (const float*)d_in[20]};
    const float* self_w[3] = {(const float*)d_in[5],  (const float*)d_in[13], (const float*)d_in[21]};
    const float* lin_b[3]  = {(const float*)d_in[6],  (const float*)d_in[14], (const float*)d_in[22]};
    const float* self_b[3] = {(const float*)d_in[7],  (const float*)d_in[15], (const float*)d_in[23]};
    const float* bn1_g[3]  = {(const float*)d_in[8],  (const float*)d_in[16], (const float*)d_in[24]};
    const float* bn1_b[3]  = {(const float*)d_in[9],  (const float*)d_in[17], (const float*)d_in[25]};
    const float* bn2_g[3]  = {(const float*)d_in[10], (const float*)d_in[18], (const float*)d_in[26]};
    const float* bn2_b[3]  = {(const float*)d_in[11], (const float*)d_in[19], (const float*)d_in[27]};

    char* ws = (char*)d_ws;
    size_t off = 0;
    auto alloc = [&](size_t bytes)->char*{ char* p = ws + off; off = align256(off + bytes); return p; };

    int*     seg_start  = (int*)alloc((size_t)(NSEG+1)*4);
    int*     bsum       = (int*)alloc(1024*4);
    int*     src_sorted = (int*)alloc((size_t)NE*4);
    float*   stats      = (float*)alloc((size_t)8*DH*4);
    float*   sums1 = stats;            float* sums2 = stats + 2*DH;
    float*   ac1   = stats + 4*DH;     float* ac2   = stats + 6*DH;
    ushortT* hbf    = (ushortT*)alloc((size_t)NN*DH*2);
    ushortT* Wcat   = (ushortT*)alloc((size_t)DH*4096*2);

    // Acat takes the remainder. counts/cursor (CSR) and Acat0 (layer 0) are aliased
    // into the Acat region — all dead before the first layer-1 segsum write (stream-serial).
    size_t remain = (ws_size > off) ? (ws_size - off) : 0;
    ushortT* Acat   = (ushortT*)(ws + off);
    int*     counts = (int*)Acat;
    int*     cursor = counts + NSEG;
    ushortT* Acat0  = (ushortT*)align256((size_t)(cursor + NSEG));

    long max_nodes = (long)(remain / ((size_t)KSEG*2));
    int chunk;
    if (max_nodes >= NN) chunk = NN;
    else { chunk = (int)(max_nodes & ~127L); if (chunk < 2560) chunk = 2560; }

    // CSR build (graph is layer-invariant)
    hipMemsetAsync(counts, 0, (size_t)NSEG*4, stream);
    hipMemsetAsync(cursor, 0, (size_t)NSEG*4, stream);
    hist_k<<<(NE+255)/256, 256, 0, stream>>>(dst, rel, counts);
    int nb = (NSEG + 1023)/1024;
    scan1_k<<<nb, 256, 0, stream>>>(counts, bsum);
    scan2_k<<<1, 256, 0, stream>>>(bsum, nb, seg_start);
    scan3_k<<<nb, 256, 0, stream>>>(counts, bsum, seg_start);
    scatter_k<<<(NE+255)/256, 256, 0, stream>>>(src, dst, rel, seg_start, cursor, src_sorted);

    float* dout = (float*)d_out;

    for (int layer = 0; layer < 3; layer++){
        int d  = (layer == 0) ? DIN : DH;
        int Kp = (layer == 0) ? 192 : 4096;
        convw_k<<<(DH*Kp + 255)/256, 256, 0, stream>>>(lin_w[layer], self_w[layer], d, Kp, Wcat);
        hipMemsetAsync(stats, 0, (size_t)4*DH*4, stream);   // sums1 + sums2

        if (layer == 0){
            segsum21b_k<<<NN, 64, 0, stream>>>(x0, seg_start, src_sorted, Acat0);
            gemm_mfma_k<<<((NN + 127)/128)*4, 256, 0, stream>>>(
                Acat0, 192, 6, Acat0, NN, Wcat, 192,
                lin_b[layer], self_b[layer],
                dout + layer*DH, 3*DH, 6, sums1);
        } else {
            for (int c0 = 0; c0 < NN; c0 += chunk){
                int cn = (NN - c0 < chunk) ? (NN - c0) : chunk;
                int sgrid = (cn + 3)/4; if (sgrid > 2048) sgrid = 2048;
                segsum_wave_k<<<sgrid, 256, 0, stream>>>(
                    hbf, seg_start, src_sorted, Acat, c0, cn);
                gemm_mfma_k<<<((cn + 127)/128)*4, 256, 0, stream>>>(
                    Acat, KSEG, 112, hbf + (long)c0*DH, cn, Wcat, 4096,
                    lin_b[layer], self_b[layer],
                    dout + (long)c0*(3*DH) + layer*DH, 3*DH, 128, sums1);
            }
        }

        finalize_k<<<2, 256, 0, stream>>>(sums1, bn1_g[layer], bn1_b[layer], ac1);
        bnrelu_k<<<dim3(2, (NN+127)/128), 256, 0, stream>>>(dout + layer*DH, NN, ac1, sums2);
        finalize_k<<<2, 256, 0, stream>>>(sums2, bn2_g[layer], bn2_b[layer], ac2);
        bn2write_k<<<((long)NN*DH + 255)/256, 256, 0, stream>>>(dout + layer*DH, ac2, hbf);
    }
}

// Round 17
// 992.683 us; speedup vs baseline: 1.0922x; 1.0922x over previous
//
#include <hip/hip_runtime.h>

#define NN   30000
#define NE   480000
#define NR   7
#define NSEG (NN*NR)
#define DH   512
#define DIN  21
#define EPSB 1e-5f
#define KSEG 3584          // 7*512 gathered columns (self handled from hbf)

typedef __attribute__((ext_vector_type(8))) short bf16x8;
typedef __attribute__((ext_vector_type(8))) unsigned short u16x8;
typedef __attribute__((ext_vector_type(4))) float f32x4;
typedef unsigned short ushortT;

static inline size_t align256(size_t x){ return (x + 255) & ~(size_t)255; }

__device__ inline float bf2f(ushortT u){
    unsigned int i = ((unsigned int)u) << 16; float f; __builtin_memcpy(&f, &i, 4); return f;
}
__device__ inline ushortT f2bf(float f){
    unsigned int i; __builtin_memcpy(&i, &f, 4);
    unsigned int r = i + 0x7FFFu + ((i >> 16) & 1u);
    return (ushortT)(r >> 16);
}

__device__ inline void load_lds16(const ushortT* g, ushortT* l){
    __builtin_amdgcn_global_load_lds((const __attribute__((address_space(1))) unsigned int*)g,
                                     (__attribute__((address_space(3))) unsigned int*)l,
                                     16, 0, 0);
}

// ---------------- CSR build (counting sort by seg = dst*7+rel) ----------------

__global__ void hist_k(const int* __restrict__ dst, const int* __restrict__ rel,
                       int* __restrict__ counts){
    int e = blockIdx.x*256 + threadIdx.x;
    if (e < NE) atomicAdd(&counts[dst[e]*NR + rel[e]], 1);
}

__global__ void scan1_k(const int* __restrict__ counts, int* __restrict__ bsum){
    __shared__ int sd[256];
    int t = threadIdx.x;
    int base = blockIdx.x*1024 + t*4;
    int s = 0;
#pragma unroll
    for (int i = 0; i < 4; i++){ int idx = base + i; if (idx < NSEG) s += counts[idx]; }
    sd[t] = s; __syncthreads();
    for (int off = 128; off > 0; off >>= 1){
        if (t < off) sd[t] += sd[t+off];
        __syncthreads();
    }
    if (t == 0) bsum[blockIdx.x] = sd[0];
}

__global__ void scan2_k(int* __restrict__ bsum, int nb, int* __restrict__ seg_start){
    __shared__ int sd[256];
    int t = threadIdx.x;
    int v = (t < nb) ? bsum[t] : 0;
    sd[t] = v; __syncthreads();
    for (int off = 1; off < 256; off <<= 1){
        int x = sd[t];
        if (t >= off) x += sd[t-off];
        __syncthreads();
        sd[t] = x; __syncthreads();
    }
    if (t < nb) bsum[t] = (t == 0) ? 0 : sd[t-1];
    if (t == 0) seg_start[NSEG] = NE;
}

__global__ void scan3_k(const int* __restrict__ counts, const int* __restrict__ bsum,
                        int* __restrict__ seg_start){
    __shared__ int sd[256];
    int t = threadIdx.x;
    int base = blockIdx.x*1024 + t*4;
    int v[4]; int s = 0;
#pragma unroll
    for (int i = 0; i < 4; i++){ int idx = base + i; v[i] = (idx < NSEG) ? counts[idx] : 0; s += v[i]; }
    sd[t] = s; __syncthreads();
    for (int off = 1; off < 256; off <<= 1){
        int x = sd[t];
        if (t >= off) x += sd[t-off];
        __syncthreads();
        sd[t] = x; __syncthreads();
    }
    int excl = sd[t] - s + bsum[blockIdx.x];
#pragma unroll
    for (int i = 0; i < 4; i++){
        int idx = base + i;
        if (idx < NSEG){ seg_start[idx] = excl; excl += v[i]; }
    }
}

__global__ void scatter_k(const int* __restrict__ src, const int* __restrict__ dst,
                          const int* __restrict__ rel, const int* __restrict__ seg_start,
                          int* __restrict__ cursor, int* __restrict__ src_sorted){
    int e = blockIdx.x*256 + threadIdx.x;
    if (e < NE){
        int s = dst[e]*NR + rel[e];
        int pos = seg_start[s] + atomicAdd(&cursor[s], 1);
        src_sorted[pos] = src[e];
    }
}

// ---------------- layer 0: segment sum d=21 → Acat0[*,256] (147 upd | 21 self | pad) --------

__global__ void segsum21b_k(const float* __restrict__ x0,
                            const int* __restrict__ seg_start, const int* __restrict__ src_sorted,
                            ushortT* __restrict__ Acat0){
    int n = blockIdx.x;
    int t = threadIdx.x;   // 64
    ushortT* arow = Acat0 + (long)n*256;
    if (t < DIN){
        int sb = n*NR;
        int e0 = seg_start[sb];
#pragma unroll
        for (int r = 0; r < NR; r++){
            int e1 = seg_start[sb + r + 1];
            float a = 0.f;
            for (int e = e0; e < e1; e++) a += x0[(long)src_sorted[e]*DIN + t];
            e0 = e1;
            arow[r*DIN + t] = f2bf(a);
        }
        arow[7*DIN + t] = f2bf(x0[(long)n*DIN + t]);
    }
    if (t >= 40) arow[168 + (t - 40)] = 0;   // 168..191
    arow[192 + t] = 0;                        // 192..255
}

// ---------------- segsum (layers 1,2): one WAVE per node → Acat[*,3584], grid-stride --------

__device__ inline void segsum_body(const ushortT* __restrict__ hbf,
                                   const int* __restrict__ seg_start,
                                   const int* __restrict__ src_sorted,
                                   ushortT* __restrict__ Acat,
                                   int wid, int c0, int lane){
    const int n = c0 + wid;
    const int co = lane*8;

    int sb[8];
#pragma unroll
    for (int i = 0; i < 8; i++) sb[i] = seg_start[n*NR + i];

    ushortT* arow = Acat + (long)wid*KSEG + co;
#pragma unroll
    for (int r = 0; r < NR; r++){
        float a[8];
#pragma unroll
        for (int j = 0; j < 8; j++) a[j] = 0.f;
        int e = sb[r], e1 = sb[r+1];
        for (; e + 3 < e1; e += 4){
            u16x8 v0 = *reinterpret_cast<const u16x8*>(hbf + (long)src_sorted[e  ]*DH + co);
            u16x8 v1 = *reinterpret_cast<const u16x8*>(hbf + (long)src_sorted[e+1]*DH + co);
            u16x8 v2 = *reinterpret_cast<const u16x8*>(hbf + (long)src_sorted[e+2]*DH + co);
            u16x8 v3 = *reinterpret_cast<const u16x8*>(hbf + (long)src_sorted[e+3]*DH + co);
#pragma unroll
            for (int j = 0; j < 8; j++)
                a[j] += (bf2f((ushortT)v0[j]) + bf2f((ushortT)v1[j]))
                      + (bf2f((ushortT)v2[j]) + bf2f((ushortT)v3[j]));
        }
        for (; e < e1; e++){
            u16x8 v = *reinterpret_cast<const u16x8*>(hbf + (long)src_sorted[e]*DH + co);
#pragma unroll
            for (int j = 0; j < 8; j++) a[j] += bf2f((ushortT)v[j]);
        }
        u16x8 o;
#pragma unroll
        for (int j = 0; j < 8; j++) o[j] = f2bf(a[j]);
        *reinterpret_cast<u16x8*>(arow + r*DH) = o;
    }
}

__global__ __launch_bounds__(256)
void segsum_wave_k(const ushortT* __restrict__ hbf,
                   const int* __restrict__ seg_start, const int* __restrict__ src_sorted,
                   ushortT* __restrict__ Acat, int c0, int cn){
    const int lane = threadIdx.x & 63;
    const int gwave = (blockIdx.x*256 + threadIdx.x) >> 6;
    const int nwaves = (gridDim.x*256) >> 6;
    for (int wid = gwave; wid < cn; wid += nwaves)
        segsum_body(hbf, seg_start, src_sorted, Acat, wid, c0, lane);
}

// ---------------- weight concat + bf16 convert: Wcat[512][Kp] ----------------

__global__ void convw_k(const float* __restrict__ lw, const float* __restrict__ sw,
                        int d, int Kp, ushortT* __restrict__ Wc){
    int i = blockIdx.x*256 + threadIdx.x;
    if (i < DH*Kp){
        int n = i / Kp, k = i % Kp;
        float v;
        if (k < 7*d)      v = lw[(long)n*7*d + k];
        else if (k < 8*d) v = sw[(long)n*d + (k - 7*d)];
        else              v = 0.f;
        Wc[i] = f2bf(v);
    }
}

// ---------------- 8-phase 128x256 MFMA GEMM (T2+T3+T4+T5) ----------------
// 8 waves (2M x 4N of 64x64), BK=64, LDS = As 32KB (2buf x 2half x [64][64]) +
// Bs 64KB (2buf x 2half x [128][64]) = 96 KB. Grid = panels*2 = 470 (all CUs busy).
// A-half = 1 load/thread, B-half = 2. Counted guards: vmcnt(2) at ph3 (B1 landed) and
// ph7 (A2+B2 landed) — never drains the pipeline. A frags reg-hoisted ph0/ph1 so A-LDS
// is dead from ph2; each phase stages exactly one half-tile into a dead region.
// T2 swizzle both sides. C written fp32 to d_out slice (ldc), fused col-stats.

__global__ __launch_bounds__(512, 2)
void gemm8_k(const ushortT* __restrict__ A, int lda, int ntA,
             const ushortT* __restrict__ hbase, int M,
             const ushortT* __restrict__ W, int ldw,
             const float* __restrict__ b1, const float* __restrict__ b2,
             float* __restrict__ C, int ldc, int nt, float* __restrict__ sums){
    __shared__ ushortT As[2*2*64*64];    // 32 KB: [buf][half][64][64]
    __shared__ ushortT Bs[2*2*128*64];   // 64 KB: [buf][half][128][64]
    const int t = threadIdx.x;

    // bijective XCD swizzle; panel = l>>1, col-tile = l&1
    const int nwg = gridDim.x;
    int qq = nwg >> 3, rr = nwg & 7;
    int xcd = blockIdx.x & 7, slot = blockIdx.x >> 3;
    int l = xcd*qq + min(xcd, rr) + slot;
    const int bm = (l >> 1)*128;
    const int bn = (l & 1)*256;

    // staging: A half = 512 units (1/thread), B half = 1024 units (2/thread)
    const int ur  = t >> 3;              // 0..63
    const int sw  = ((t & 7) ^ (ur & 7))*8;
    const int ur1 = 64 + ur;             // unit t+512 row
    const int sw1 = ((t & 7) ^ (ur1 & 7))*8;
    const int arh0 = min(bm + ur, M-1);
    const int arh1 = min(bm + 64 + ur, M-1);
    const int brA0 = bn + ur,        brA1 = bn + ur1;        // B half 0 rows
    const int brB0 = bn + 128 + ur,  brB1 = bn + 128 + ur1;  // B half 1 rows

    auto stageA = [&](int kt, int h, int buf){
        ushortT* d = &As[(buf*2 + h)*4096];
        int row = h ? arh1 : arh0;
        const ushortT* p;
        if (kt < ntA) p = A + (long)row*lda + kt*64 + sw;
        else          p = hbase + (long)row*DH + (kt - ntA)*64 + sw;
        load_lds16(p, d + t*8);
    };
    auto stageB = [&](int kt, int h, int buf){
        ushortT* d = &Bs[(buf*2 + h)*8192];
        int r0 = h ? brB0 : brA0, r1 = h ? brB1 : brA1;
        load_lds16(W + (long)r0*ldw + kt*64 + sw,  d + t*8);
        load_lds16(W + (long)r1*ldw + kt*64 + sw1, d + (t + 512)*8);
    };

    // fragment constants
    const int w = t >> 6, lane = t & 63;
    const int wm = w >> 2, wn = w & 3;          // 2M x 4N, wave tile 64x64
    const int r = lane & 15, hi = lane >> 4;
    const int swzk0 = ((hi)     ^ (r & 7))*8;   // ks=0
    const int swzk1 = ((4 + hi) ^ (r & 7))*8;   // ks=1
    const int aBase = wm*4096 + r*64;                          // + buf*8192
    const int bBase = (wn >> 1)*8192 + ((wn & 1)*64 + r)*64;   // + buf*16384

    f32x4 acc[4][4];
#pragma unroll
    for (int m = 0; m < 4; m++)
#pragma unroll
        for (int n = 0; n < 4; n++) acc[m][n] = (f32x4){0.f,0.f,0.f,0.f};

    // prologue: tile0 A+B -> buf0 (6 loads), tile1 A -> buf1 (2 loads)
    stageA(0, 0, 0); stageA(0, 1, 0);
    stageB(0, 0, 0); stageB(0, 1, 0);
    stageA(1, 0, 1); stageA(1, 1, 1);
    asm volatile("s_waitcnt vmcnt(2)" ::: "memory");   // tile0 landed, tile1-A in flight
    __builtin_amdgcn_s_barrier();

    for (int it = 0; it < nt; it += 2){
#pragma unroll
        for (int b = 0; b < 2; ++b){
            bf16x8 aK0[4], aK1[4];
            const int bufoA = b*8192;
            const int bufoB = b*16384;
#pragma unroll
            for (int qp = 0; qp < 4; ++qp){
                const int np = qp >> 1;
                const int swzk = (qp & 1) ? swzk1 : swzk0;
                // ds reads for this phase
                bf16x8 bb0 = *reinterpret_cast<const bf16x8*>(&Bs[bufoB + bBase + (np*2+0)*1024 + swzk]);
                bf16x8 bb1 = *reinterpret_cast<const bf16x8*>(&Bs[bufoB + bBase + (np*2+1)*1024 + swzk]);
                if (qp == 0){
#pragma unroll
                    for (int m = 0; m < 4; m++)
                        aK0[m] = *reinterpret_cast<const bf16x8*>(&As[bufoA + aBase + m*1024 + swzk0]);
                }
                if (qp == 1){
#pragma unroll
                    for (int m = 0; m < 4; m++)
                        aK1[m] = *reinterpret_cast<const bf16x8*>(&As[bufoA + aBase + m*1024 + swzk1]);
                }
                // stage one half-tile into a dead region
                {
                    const int ph = b*4 + qp;
                    if (ph == 0)      stageB(min(it+1, nt-1), 0, 1);
                    else if (ph == 1) stageB(min(it+1, nt-1), 1, 1);
                    else if (ph == 2) stageA(min(it+2, nt-1), 0, 0);
                    else if (ph == 3) stageA(min(it+2, nt-1), 1, 0);
                    else if (ph == 4) stageB(min(it+2, nt-1), 0, 0);
                    else if (ph == 5) stageB(min(it+2, nt-1), 1, 0);
                    else if (ph == 6) stageA(min(it+3, nt-1), 0, 1);
                    else              stageA(min(it+3, nt-1), 1, 1);
                }
                __builtin_amdgcn_s_barrier();
                asm volatile("s_waitcnt lgkmcnt(0)" ::: "memory");
                __builtin_amdgcn_sched_barrier(0);
                __builtin_amdgcn_s_setprio(1);
#pragma unroll
                for (int m = 0; m < 4; m++){
                    const bf16x8 am = (qp & 1) ? aK1[m] : aK0[m];
                    acc[m][np*2+0] = __builtin_amdgcn_mfma_f32_16x16x32_bf16(am, bb0, acc[m][np*2+0], 0, 0, 0);
                    acc[m][np*2+1] = __builtin_amdgcn_mfma_f32_16x16x32_bf16(am, bb1, acc[m][np*2+1], 0, 0, 0);
                }
                __builtin_amdgcn_s_setprio(0);
                if (qp == 3) asm volatile("s_waitcnt vmcnt(2)" ::: "memory");  // next buf's halves landed
                __builtin_amdgcn_s_barrier();
            }
        }
    }
    asm volatile("s_waitcnt vmcnt(0)" ::: "memory");

    // epilogue: bias + fp32 store + fused column stats
#pragma unroll
    for (int n = 0; n < 4; n++){
        int col = bn + wn*64 + n*16 + r;
        float bb = b1[col] + b2[col];
        float s = 0.f, s2 = 0.f;
#pragma unroll
        for (int m = 0; m < 4; m++){
            int row = bm + wm*64 + m*16 + hi*4;
#pragma unroll
            for (int j2 = 0; j2 < 4; j2++){
                if (row + j2 < M){
                    float v = acc[m][n][j2] + bb;
                    C[(long)(row + j2)*ldc + col] = v;
                    s += v; s2 = fmaf(v, v, s2);
                }
            }
        }
        s  += __shfl_xor(s, 16);  s  += __shfl_xor(s, 32);
        s2 += __shfl_xor(s2, 16); s2 += __shfl_xor(s2, 32);
        if (hi == 0){
            atomicAdd(&sums[col], s);
            atomicAdd(&sums[DH + col], s2);
        }
    }
}

// ---------------- BatchNorm passes (fp32 in d_out, in place) ----------------

__global__ void finalize_k(const float* __restrict__ sums, const float* __restrict__ g,
                           const float* __restrict__ b, float* __restrict__ ac){
    int c = blockIdx.x*256 + threadIdx.x;
    if (c < DH){
        float mu  = sums[c] * (1.f/NN);
        float var = sums[DH + c] * (1.f/NN) - mu*mu;
        var = fmaxf(var, 0.f);
        float a = g[c] * rsqrtf(var + EPSB);
        ac[c]      = a;
        ac[DH + c] = fmaf(-mu, a, b[c]);
    }
}

__global__ void bnrelu_k(float* __restrict__ o, int M, const float* __restrict__ ac,
                         float* __restrict__ sums2){
    int col = blockIdx.x*256 + threadIdx.x;
    int r0 = blockIdx.y*128;
    int r1 = min(r0 + 128, M);
    float a = ac[col], c = ac[DH + col];
    float s = 0.f, s2 = 0.f;
    for (int r = r0; r < r1; r++){
        long idx = (long)r*(3*DH) + col;
        float y = fmaxf(fmaf(a, o[idx], c), 0.f);
        o[idx] = y;
        s += y; s2 = fmaf(y, y, s2);
    }
    atomicAdd(&sums2[col], s);
    atomicAdd(&sums2[DH + col], s2);
}

__global__ void bn2write_k(float* __restrict__ o, const float* __restrict__ ac,
                           ushortT* __restrict__ hbf){
    long i = (long)blockIdx.x*256 + threadIdx.x;
    if (i < (long)NN*DH){
        int r = (int)(i >> 9);
        int c = (int)(i & 511);
        long idx = (long)r*(3*DH) + c;
        float h = fmaf(ac[c], o[idx], ac[DH + c]);
        o[idx] = h;
        hbf[i] = f2bf(h);
    }
}

// ---------------- driver ----------------

extern "C" void kernel_launch(void* const* d_in, const int* in_sizes, int n_in,
                              void* d_out, int out_size, void* d_ws, size_t ws_size,
                              hipStream_t stream){
    const float* x0  = (const float*)d_in[0];
    const int*   src = (const int*)d_in[1];
    const int*   dst = (const int*)d_in[2];
    const int*   rel = (const int*)d_in[3];
    const float* lin_w[3]  = {(const float*)d_in[4],  (const float*)d_in[12], (const float*)d_in[20]};
    const float* self_w[3] = {(const float*)d_in[5],  (const float*)d_in[13], (const float*)d_in[21]};
    const float* lin_b[3]  = {(const float*)d_in[6],  (const float*)d_in[14], (const float*)d_in[22]};
    const float* self_b[3] = {(const float*)d_in[7],  (const float*)d_in[15], (const float*)d_in[23]};
    const float* bn1_g[3]  = {(const float*)d_in[8],  (const float*)d_in[16], (const float*)d_in[24]};
    const float* bn1_b[3]  = {(const float*)d_in[9],  (const float*)d_in[17], (const float*)d_in[25]};
    const float* bn2_g[3]  = {(const float*)d_in[10], (const float*)d_in[18], (const float*)d_in[26]};
    const float* bn2_b[3]  = {(const float*)d_in[11], (const float*)d_in[19], (const float*)d_in[27]};

    char* ws = (char*)d_ws;
    size_t off = 0;
    auto alloc = [&](size_t bytes)->char*{ char* p = ws + off; off = align256(off + bytes); return p; };

    int*     seg_start  = (int*)alloc((size_t)(NSEG+1)*4);
    int*     bsum       = (int*)alloc(1024*4);
    int*     src_sorted = (int*)alloc((size_t)NE*4);
    float*   stats      = (float*)alloc((size_t)8*DH*4);
    float*   sums1 = stats;            float* sums2 = stats + 2*DH;
    float*   ac1   = stats + 4*DH;     float* ac2   = stats + 6*DH;
    ushortT* hbf    = (ushortT*)alloc((size_t)NN*DH*2);
    ushortT* Wcat   = (ushortT*)alloc((size_t)DH*4096*2);

    // Acat takes the remainder. counts/cursor (CSR) and Acat0 (layer 0) are aliased
    // into the Acat region — all dead before the first layer-1 segsum write (stream-serial).
    size_t remain = (ws_size > off) ? (ws_size - off) : 0;
    ushortT* Acat   = (ushortT*)(ws + off);
    int*     counts = (int*)Acat;
    int*     cursor = counts + NSEG;
    ushortT* Acat0  = (ushortT*)align256((size_t)(cursor + NSEG));

    long max_nodes = (long)(remain / ((size_t)KSEG*2));
    int chunk;
    if (max_nodes >= NN) chunk = NN;
    else { chunk = (int)(max_nodes & ~255L); if (chunk < 2560) chunk = 2560; }

    // CSR build (graph is layer-invariant)
    hipMemsetAsync(counts, 0, (size_t)NSEG*4, stream);
    hipMemsetAsync(cursor, 0, (size_t)NSEG*4, stream);
    hist_k<<<(NE+255)/256, 256, 0, stream>>>(dst, rel, counts);
    int nb = (NSEG + 1023)/1024;
    scan1_k<<<nb, 256, 0, stream>>>(counts, bsum);
    scan2_k<<<1, 256, 0, stream>>>(bsum, nb, seg_start);
    scan3_k<<<nb, 256, 0, stream>>>(counts, bsum, seg_start);
    scatter_k<<<(NE+255)/256, 256, 0, stream>>>(src, dst, rel, seg_start, cursor, src_sorted);

    float* dout = (float*)d_out;

    for (int layer = 0; layer < 3; layer++){
        int d  = (layer == 0) ? DIN : DH;
        int Kp = (layer == 0) ? 256 : 4096;
        convw_k<<<(DH*Kp + 255)/256, 256, 0, stream>>>(lin_w[layer], self_w[layer], d, Kp, Wcat);
        hipMemsetAsync(stats, 0, (size_t)4*DH*4, stream);   // sums1 + sums2

        if (layer == 0){
            segsum21b_k<<<NN, 64, 0, stream>>>(x0, seg_start, src_sorted, Acat0);
            gemm8_k<<<((NN + 127)/128)*2, 512, 0, stream>>>(
                Acat0, 256, 4, Acat0, NN, Wcat, 256,
                lin_b[layer], self_b[layer],
                dout + layer*DH, 3*DH, 4, sums1);
        } else {
            for (int c0 = 0; c0 < NN; c0 += chunk){
                int cn = (NN - c0 < chunk) ? (NN - c0) : chunk;
                int sgrid = (cn + 3)/4; if (sgrid > 2048) sgrid = 2048;
                segsum_wave_k<<<sgrid, 256, 0, stream>>>(
                    hbf, seg_start, src_sorted, Acat, c0, cn);
                gemm8_k<<<((cn + 127)/128)*2, 512, 0, stream>>>(
                    Acat, KSEG, 56, hbf + (long)c0*DH, cn, Wcat, 4096,
                    lin_b[layer], self_b[layer],
                    dout + (long)c0*(3*DH) + layer*DH, 3*DH, 64, sums1);
            }
        }

        finalize_k<<<2, 256, 0, stream>>>(sums1, bn1_g[layer], bn1_b[layer], ac1);
        bnrelu_k<<<dim3(2, (NN+127)/128), 256, 0, stream>>>(dout + layer*DH, NN, ac1, sums2);
        finalize_k<<<2, 256, 0, stream>>>(sums2, bn2_g[layer], bn2_b[layer], ac2);
        bn2write_k<<<((long)NN*DH + 255)/256, 256, 0, stream>>>(dout + layer*DH, ac2, hbf);
    }
}

// Round 18
// 951.899 us; speedup vs baseline: 1.1390x; 1.0428x over previous
//
#include <hip/hip_runtime.h>

#define NN   30000
#define NE   480000
#define NR   7
#define NSEG (NN*NR)
#define DH   512
#define DIN  21
#define EPSB 1e-5f
#define KSEG 3584          // 7*512 gathered columns (self handled from hbf)

typedef __attribute__((ext_vector_type(8))) short bf16x8;
typedef __attribute__((ext_vector_type(8))) unsigned short u16x8;
typedef __attribute__((ext_vector_type(4))) float f32x4;
typedef unsigned short ushortT;

static inline size_t align256(size_t x){ return (x + 255) & ~(size_t)255; }

__device__ inline float bf2f(ushortT u){
    unsigned int i = ((unsigned int)u) << 16; float f; __builtin_memcpy(&f, &i, 4); return f;
}
__device__ inline ushortT f2bf(float f){
    unsigned int i; __builtin_memcpy(&i, &f, 4);
    unsigned int r = i + 0x7FFFu + ((i >> 16) & 1u);
    return (ushortT)(r >> 16);
}

__device__ inline void load_lds16(const ushortT* g, ushortT* l){
    __builtin_amdgcn_global_load_lds((const __attribute__((address_space(1))) unsigned int*)g,
                                     (__attribute__((address_space(3))) unsigned int*)l,
                                     16, 0, 0);
}

// ---------------- CSR build (counting sort by seg = dst*7+rel) ----------------

__global__ void hist_k(const int* __restrict__ dst, const int* __restrict__ rel,
                       int* __restrict__ counts){
    int e = blockIdx.x*256 + threadIdx.x;
    if (e < NE) atomicAdd(&counts[dst[e]*NR + rel[e]], 1);
}

__global__ void scan1_k(const int* __restrict__ counts, int* __restrict__ bsum){
    __shared__ int sd[256];
    int t = threadIdx.x;
    int base = blockIdx.x*1024 + t*4;
    int s = 0;
#pragma unroll
    for (int i = 0; i < 4; i++){ int idx = base + i; if (idx < NSEG) s += counts[idx]; }
    sd[t] = s; __syncthreads();
    for (int off = 128; off > 0; off >>= 1){
        if (t < off) sd[t] += sd[t+off];
        __syncthreads();
    }
    if (t == 0) bsum[blockIdx.x] = sd[0];
}

__global__ void scan2_k(int* __restrict__ bsum, int nb, int* __restrict__ seg_start){
    __shared__ int sd[256];
    int t = threadIdx.x;
    int v = (t < nb) ? bsum[t] : 0;
    sd[t] = v; __syncthreads();
    for (int off = 1; off < 256; off <<= 1){
        int x = sd[t];
        if (t >= off) x += sd[t-off];
        __syncthreads();
        sd[t] = x; __syncthreads();
    }
    if (t < nb) bsum[t] = (t == 0) ? 0 : sd[t-1];
    if (t == 0) seg_start[NSEG] = NE;
}

__global__ void scan3_k(const int* __restrict__ counts, const int* __restrict__ bsum,
                        int* __restrict__ seg_start){
    __shared__ int sd[256];
    int t = threadIdx.x;
    int base = blockIdx.x*1024 + t*4;
    int v[4]; int s = 0;
#pragma unroll
    for (int i = 0; i < 4; i++){ int idx = base + i; v[i] = (idx < NSEG) ? counts[idx] : 0; s += v[i]; }
    sd[t] = s; __syncthreads();
    for (int off = 1; off < 256; off <<= 1){
        int x = sd[t];
        if (t >= off) x += sd[t-off];
        __syncthreads();
        sd[t] = x; __syncthreads();
    }
    int excl = sd[t] - s + bsum[blockIdx.x];
#pragma unroll
    for (int i = 0; i < 4; i++){
        int idx = base + i;
        if (idx < NSEG){ seg_start[idx] = excl; excl += v[i]; }
    }
}

__global__ void scatter_k(const int* __restrict__ src, const int* __restrict__ dst,
                          const int* __restrict__ rel, const int* __restrict__ seg_start,
                          int* __restrict__ cursor, int* __restrict__ src_sorted){
    int e = blockIdx.x*256 + threadIdx.x;
    if (e < NE){
        int s = dst[e]*NR + rel[e];
        int pos = seg_start[s] + atomicAdd(&cursor[s], 1);
        src_sorted[pos] = src[e];
    }
}

// ---------------- layer 0: segment sum d=21 → Acat0[*,256] (147 upd | 21 self | pad) --------

__global__ void segsum21b_k(const float* __restrict__ x0,
                            const int* __restrict__ seg_start, const int* __restrict__ src_sorted,
                            ushortT* __restrict__ Acat0){
    int n = blockIdx.x;
    int t = threadIdx.x;   // 64
    ushortT* arow = Acat0 + (long)n*256;
    if (t < DIN){
        int sb = n*NR;
        int e0 = seg_start[sb];
#pragma unroll
        for (int r = 0; r < NR; r++){
            int e1 = seg_start[sb + r + 1];
            float a = 0.f;
            for (int e = e0; e < e1; e++) a += x0[(long)src_sorted[e]*DIN + t];
            e0 = e1;
            arow[r*DIN + t] = f2bf(a);
        }
        arow[7*DIN + t] = f2bf(x0[(long)n*DIN + t]);
    }
    if (t >= 40) arow[168 + (t - 40)] = 0;   // 168..191
    arow[192 + t] = 0;                        // 192..255
}

// ---------------- segsum (layers 1,2): one WAVE per node → Acat[*,3584], grid-stride --------

__device__ inline void segsum_body(const ushortT* __restrict__ hbf,
                                   const int* __restrict__ seg_start,
                                   const int* __restrict__ src_sorted,
                                   ushortT* __restrict__ Acat,
                                   int wid, int c0, int lane){
    const int n = c0 + wid;
    const int co = lane*8;

    int sb[8];
#pragma unroll
    for (int i = 0; i < 8; i++) sb[i] = seg_start[n*NR + i];

    ushortT* arow = Acat + (long)wid*KSEG + co;
#pragma unroll
    for (int r = 0; r < NR; r++){
        float a[8];
#pragma unroll
        for (int j = 0; j < 8; j++) a[j] = 0.f;
        int e = sb[r], e1 = sb[r+1];
        for (; e + 3 < e1; e += 4){
            u16x8 v0 = *reinterpret_cast<const u16x8*>(hbf + (long)src_sorted[e  ]*DH + co);
            u16x8 v1 = *reinterpret_cast<const u16x8*>(hbf + (long)src_sorted[e+1]*DH + co);
            u16x8 v2 = *reinterpret_cast<const u16x8*>(hbf + (long)src_sorted[e+2]*DH + co);
            u16x8 v3 = *reinterpret_cast<const u16x8*>(hbf + (long)src_sorted[e+3]*DH + co);
#pragma unroll
            for (int j = 0; j < 8; j++)
                a[j] += (bf2f((ushortT)v0[j]) + bf2f((ushortT)v1[j]))
                      + (bf2f((ushortT)v2[j]) + bf2f((ushortT)v3[j]));
        }
        for (; e < e1; e++){
            u16x8 v = *reinterpret_cast<const u16x8*>(hbf + (long)src_sorted[e]*DH + co);
#pragma unroll
            for (int j = 0; j < 8; j++) a[j] += bf2f((ushortT)v[j]);
        }
        u16x8 o;
#pragma unroll
        for (int j = 0; j < 8; j++) o[j] = f2bf(a[j]);
        *reinterpret_cast<u16x8*>(arow + r*DH) = o;
    }
}

__global__ __launch_bounds__(256)
void segsum_wave_k(const ushortT* __restrict__ hbf,
                   const int* __restrict__ seg_start, const int* __restrict__ src_sorted,
                   ushortT* __restrict__ Acat, int c0, int cn){
    const int lane = threadIdx.x & 63;
    const int gwave = (blockIdx.x*256 + threadIdx.x) >> 6;
    const int nwaves = (gridDim.x*256) >> 6;
    for (int wid = gwave; wid < cn; wid += nwaves)
        segsum_body(hbf, seg_start, src_sorted, Acat, wid, c0, lane);
}

// ---------------- weight concat + bf16 convert: Wcat[512][Kp] ----------------

__global__ void convw_k(const float* __restrict__ lw, const float* __restrict__ sw,
                        int d, int Kp, ushortT* __restrict__ Wc){
    int i = blockIdx.x*256 + threadIdx.x;
    if (i < DH*Kp){
        int n = i / Kp, k = i % Kp;
        float v;
        if (k < 7*d)      v = lw[(long)n*7*d + k];
        else if (k < 8*d) v = sw[(long)n*d + (k - 7*d)];
        else              v = 0.f;
        Wc[i] = f2bf(v);
    }
}

// ---------------- 1-phase-per-K-tile 128x256 MFMA GEMM (T2+T4+T5, 32 MFMA/phase) -----------
// 8 waves (2M x 4N of 64x64), BK=64. LDS: As 3-buf (48 KB, HBM-sourced A gets ~2-tile lead)
// + Bs 2-buf (64 KB, L2-resident W needs 1-tile lead) = 112 KB. Grid = panels*2 = 470.
// Per K-tile: read ALL 16 frags, one lgkmcnt(0), 32 MFMA under setprio, stage B(j+1)+A(j+2),
// guard vmcnt(2) (keeps only A(j+2) in flight), ONE barrier. Phase overhead amortized 2x
// vs R17's 8-MFMA phases. T2 swizzle both sides. fp32 C into d_out slice, fused col-stats.

__global__ __launch_bounds__(512, 2)
void gemm3_k(const ushortT* __restrict__ A, int lda, int ntA,
             const ushortT* __restrict__ hbase, int M,
             const ushortT* __restrict__ W, int ldw,
             const float* __restrict__ b1, const float* __restrict__ b2,
             float* __restrict__ C, int ldc, int nt, float* __restrict__ sums){
    __shared__ ushortT As[3*2*64*64];    // 48 KB: [abuf][half][64][64]
    __shared__ ushortT Bs[2*2*128*64];   // 64 KB: [bbuf][half][128][64]
    const int t = threadIdx.x;

    // bijective XCD swizzle; panel = l>>1, col-tile = l&1
    const int nwg = gridDim.x;
    int qq = nwg >> 3, rr = nwg & 7;
    int xcd = blockIdx.x & 7, slot = blockIdx.x >> 3;
    int l = xcd*qq + min(xcd, rr) + slot;
    const int bm = (l >> 1)*128;
    const int bn = (l & 1)*256;

    // staging: A half = 512 units (1 load/thread), B half = 1024 units (2 loads/thread)
    const int ur  = t >> 3;              // 0..63
    const int sw  = ((t & 7) ^ (ur & 7))*8;
    const int ur1 = 64 + ur;             // unit t+512 row (B halves)
    const int sw1 = ((t & 7) ^ (ur1 & 7))*8;
    const int arh0 = min(bm + ur, M-1);
    const int arh1 = min(bm + 64 + ur, M-1);
    const int brA0 = bn + ur,        brA1 = bn + ur1;        // B half 0 rows
    const int brB0 = bn + 128 + ur,  brB1 = bn + 128 + ur1;  // B half 1 rows

    auto stageA = [&](int kt, int buf){          // both halves: 2 loads
        ushortT* d = &As[buf*8192];
        const ushortT* p0;
        const ushortT* p1;
        if (kt < ntA){
            p0 = A + (long)arh0*lda + kt*64 + sw;
            p1 = A + (long)arh1*lda + kt*64 + sw;
        } else {
            int k0 = (kt - ntA)*64;
            p0 = hbase + (long)arh0*DH + k0 + sw;
            p1 = hbase + (long)arh1*DH + k0 + sw;
        }
        load_lds16(p0, d + t*8);
        load_lds16(p1, d + 4096 + t*8);
    };
    auto stageB = [&](int kt, int buf){          // both halves: 4 loads
        ushortT* d = &Bs[buf*16384];
        load_lds16(W + (long)brA0*ldw + kt*64 + sw,  d + t*8);
        load_lds16(W + (long)brA1*ldw + kt*64 + sw1, d + (t + 512)*8);
        load_lds16(W + (long)brB0*ldw + kt*64 + sw,  d + 8192 + t*8);
        load_lds16(W + (long)brB1*ldw + kt*64 + sw1, d + 8192 + (t + 512)*8);
    };

    // fragment constants
    const int w = t >> 6, lane = t & 63;
    const int wm = w >> 2, wn = w & 3;          // 2M x 4N, wave tile 64x64
    const int r = lane & 15, hi = lane >> 4;
    const int swzk0 = ((hi)     ^ (r & 7))*8;   // ks=0
    const int swzk1 = ((4 + hi) ^ (r & 7))*8;   // ks=1
    const int aBase = wm*4096 + r*64;                          // + abuf*8192
    const int bBase = (wn >> 1)*8192 + ((wn & 1)*64 + r)*64;   // + bbuf*16384

    f32x4 acc[4][4];
#pragma unroll
    for (int m = 0; m < 4; m++)
#pragma unroll
        for (int n = 0; n < 4; n++) acc[m][n] = (f32x4){0.f,0.f,0.f,0.f};

    // prologue: A(0)->abuf0, B(0)->bbuf0, A(1)->abuf1; keep only A(1) in flight
    stageA(0, 0);
    stageB(0, 0);
    if (nt > 1) stageA(1, 1);
    asm volatile("s_waitcnt vmcnt(2)" ::: "memory");
    __builtin_amdgcn_s_barrier();

    for (int j = 0; j < nt; ++j){
        const int aoff = (j % 3)*8192;
        const int boff = (j & 1)*16384;

        bf16x8 aK0[4], aK1[4], bK0[4], bK1[4];
#pragma unroll
        for (int m = 0; m < 4; m++){
            aK0[m] = *reinterpret_cast<const bf16x8*>(&As[aoff + aBase + m*1024 + swzk0]);
            aK1[m] = *reinterpret_cast<const bf16x8*>(&As[aoff + aBase + m*1024 + swzk1]);
        }
#pragma unroll
        for (int n = 0; n < 4; n++){
            bK0[n] = *reinterpret_cast<const bf16x8*>(&Bs[boff + bBase + n*1024 + swzk0]);
            bK1[n] = *reinterpret_cast<const bf16x8*>(&Bs[boff + bBase + n*1024 + swzk1]);
        }

        // stage next tiles into dead regions: B(j+1) then A(j+2)
        const bool haveB = (j + 1 < nt);
        const bool haveA = (j + 2 < nt);
        if (haveB) stageB(j + 1, (j + 1) & 1);
        if (haveA) stageA(j + 2, (j + 2) % 3);

        asm volatile("s_waitcnt lgkmcnt(0)" ::: "memory");
        __builtin_amdgcn_sched_barrier(0);
        __builtin_amdgcn_s_setprio(1);
#pragma unroll
        for (int m = 0; m < 4; m++)
#pragma unroll
            for (int n = 0; n < 4; n++)
                acc[m][n] = __builtin_amdgcn_mfma_f32_16x16x32_bf16(aK0[m], bK0[n], acc[m][n], 0, 0, 0);
#pragma unroll
        for (int m = 0; m < 4; m++)
#pragma unroll
            for (int n = 0; n < 4; n++)
                acc[m][n] = __builtin_amdgcn_mfma_f32_16x16x32_bf16(aK1[m], bK1[n], acc[m][n], 0, 0, 0);
        __builtin_amdgcn_s_setprio(0);

        // guard: everything except the A(j+2) just issued must be landed
        if (haveA) asm volatile("s_waitcnt vmcnt(2)" ::: "memory");
        else       asm volatile("s_waitcnt vmcnt(0)" ::: "memory");
        __builtin_amdgcn_s_barrier();
    }

    // epilogue: bias + fp32 store + fused column stats
#pragma unroll
    for (int n = 0; n < 4; n++){
        int col = bn + wn*64 + n*16 + r;
        float bb = b1[col] + b2[col];
        float s = 0.f, s2 = 0.f;
#pragma unroll
        for (int m = 0; m < 4; m++){
            int row = bm + wm*64 + m*16 + hi*4;
#pragma unroll
            for (int j2 = 0; j2 < 4; j2++){
                if (row + j2 < M){
                    float v = acc[m][n][j2] + bb;
                    C[(long)(row + j2)*ldc + col] = v;
                    s += v; s2 = fmaf(v, v, s2);
                }
            }
        }
        s  += __shfl_xor(s, 16);  s  += __shfl_xor(s, 32);
        s2 += __shfl_xor(s2, 16); s2 += __shfl_xor(s2, 32);
        if (hi == 0){
            atomicAdd(&sums[col], s);
            atomicAdd(&sums[DH + col], s2);
        }
    }
}

// ---------------- BatchNorm passes (fp32 in d_out, in place) ----------------

__global__ void finalize_k(const float* __restrict__ sums, const float* __restrict__ g,
                           const float* __restrict__ b, float* __restrict__ ac){
    int c = blockIdx.x*256 + threadIdx.x;
    if (c < DH){
        float mu  = sums[c] * (1.f/NN);
        float var = sums[DH + c] * (1.f/NN) - mu*mu;
        var = fmaxf(var, 0.f);
        float a = g[c] * rsqrtf(var + EPSB);
        ac[c]      = a;
        ac[DH + c] = fmaf(-mu, a, b[c]);
    }
}

__global__ void bnrelu_k(float* __restrict__ o, int M, const float* __restrict__ ac,
                         float* __restrict__ sums2){
    int col = blockIdx.x*256 + threadIdx.x;
    int r0 = blockIdx.y*128;
    int r1 = min(r0 + 128, M);
    float a = ac[col], c = ac[DH + col];
    float s = 0.f, s2 = 0.f;
    for (int r = r0; r < r1; r++){
        long idx = (long)r*(3*DH) + col;
        float y = fmaxf(fmaf(a, o[idx], c), 0.f);
        o[idx] = y;
        s += y; s2 = fmaf(y, y, s2);
    }
    atomicAdd(&sums2[col], s);
    atomicAdd(&sums2[DH + col], s2);
}

__global__ void bn2write_k(float* __restrict__ o, const float* __restrict__ ac,
                           ushortT* __restrict__ hbf){
    long i = (long)blockIdx.x*256 + threadIdx.x;
    if (i < (long)NN*DH){
        int r = (int)(i >> 9);
        int c = (int)(i & 511);
        long idx = (long)r*(3*DH) + c;
        float h = fmaf(ac[c], o[idx], ac[DH + c]);
        o[idx] = h;
        hbf[i] = f2bf(h);
    }
}

// ---------------- driver ----------------

extern "C" void kernel_launch(void* const* d_in, const int* in_sizes, int n_in,
                              void* d_out, int out_size, void* d_ws, size_t ws_size,
                              hipStream_t stream){
    const float* x0  = (const float*)d_in[0];
    const int*   src = (const int*)d_in[1];
    const int*   dst = (const int*)d_in[2];
    const int*   rel = (const int*)d_in[3];
    const float* lin_w[3]  = {(const float*)d_in[4],  (const float*)d_in[12], (const float*)d_in[20]};
    const float* self_w[3] = {(const float*)d_in[5],  (const float*)d_in[13], (const float*)d_in[21]};
    const float* lin_b[3]  = {(const float*)d_in[6],  (const float*)d_in[14], (const float*)d_in[22]};
    const float* self_b[3] = {(const float*)d_in[7],  (const float*)d_in[15], (const float*)d_in[23]};
    const float* bn1_g[3]  = {(const float*)d_in[8],  (const float*)d_in[16], (const float*)d_in[24]};
    const float* bn1_b[3]  = {(const float*)d_in[9],  (const float*)d_in[17], (const float*)d_in[25]};
    const float* bn2_g[3]  = {(const float*)d_in[10], (const float*)d_in[18], (const float*)d_in[26]};
    const float* bn2_b[3]  = {(const float*)d_in[11], (const float*)d_in[19], (const float*)d_in[27]};

    char* ws = (char*)d_ws;
    size_t off = 0;
    auto alloc = [&](size_t bytes)->char*{ char* p = ws + off; off = align256(off + bytes); return p; };

    int*     seg_start  = (int*)alloc((size_t)(NSEG+1)*4);
    int*     bsum       = (int*)alloc(1024*4);
    int*     src_sorted = (int*)alloc((size_t)NE*4);
    float*   stats      = (float*)alloc((size_t)8*DH*4);
    float*   sums1 = stats;            float* sums2 = stats + 2*DH;
    float*   ac1   = stats + 4*DH;     float* ac2   = stats + 6*DH;
    ushortT* hbf    = (ushortT*)alloc((size_t)NN*DH*2);
    ushortT* Wcat   = (ushortT*)alloc((size_t)DH*4096*2);

    // Acat takes the remainder. counts/cursor (CSR) and Acat0 (layer 0) are aliased
    // into the Acat region — all dead before the first layer-1 segsum write (stream-serial).
    size_t remain = (ws_size > off) ? (ws_size - off) : 0;
    ushortT* Acat   = (ushortT*)(ws + off);
    int*     counts = (int*)Acat;
    int*     cursor = counts + NSEG;
    ushortT* Acat0  = (ushortT*)align256((size_t)(cursor + NSEG));

    long max_nodes = (long)(remain / ((size_t)KSEG*2));
    int chunk;
    if (max_nodes >= NN) chunk = NN;
    else { chunk = (int)(max_nodes & ~255L); if (chunk < 2560) chunk = 2560; }

    // CSR build (graph is layer-invariant)
    hipMemsetAsync(counts, 0, (size_t)NSEG*4, stream);
    hipMemsetAsync(cursor, 0, (size_t)NSEG*4, stream);
    hist_k<<<(NE+255)/256, 256, 0, stream>>>(dst, rel, counts);
    int nb = (NSEG + 1023)/1024;
    scan1_k<<<nb, 256, 0, stream>>>(counts, bsum);
    scan2_k<<<1, 256, 0, stream>>>(bsum, nb, seg_start);
    scan3_k<<<nb, 256, 0, stream>>>(counts, bsum, seg_start);
    scatter_k<<<(NE+255)/256, 256, 0, stream>>>(src, dst, rel, seg_start, cursor, src_sorted);

    float* dout = (float*)d_out;

    for (int layer = 0; layer < 3; layer++){
        int d  = (layer == 0) ? DIN : DH;
        int Kp = (layer == 0) ? 256 : 4096;
        convw_k<<<(DH*Kp + 255)/256, 256, 0, stream>>>(lin_w[layer], self_w[layer], d, Kp, Wcat);
        hipMemsetAsync(stats, 0, (size_t)4*DH*4, stream);   // sums1 + sums2

        if (layer == 0){
            segsum21b_k<<<NN, 64, 0, stream>>>(x0, seg_start, src_sorted, Acat0);
            gemm3_k<<<((NN + 127)/128)*2, 512, 0, stream>>>(
                Acat0, 256, 4, Acat0, NN, Wcat, 256,
                lin_b[layer], self_b[layer],
                dout + layer*DH, 3*DH, 4, sums1);
        } else {
            for (int c0 = 0; c0 < NN; c0 += chunk){
                int cn = (NN - c0 < chunk) ? (NN - c0) : chunk;
                int sgrid = (cn + 3)/4; if (sgrid > 2048) sgrid = 2048;
                segsum_wave_k<<<sgrid, 256, 0, stream>>>(
                    hbf, seg_start, src_sorted, Acat, c0, cn);
                gemm3_k<<<((cn + 127)/128)*2, 512, 0, stream>>>(
                    Acat, KSEG, 56, hbf + (long)c0*DH, cn, Wcat, 4096,
                    lin_b[layer], self_b[layer],
                    dout + (long)c0*(3*DH) + layer*DH, 3*DH, 64, sums1);
            }
        }

        finalize_k<<<2, 256, 0, stream>>>(sums1, bn1_g[layer], bn1_b[layer], ac1);
        bnrelu_k<<<dim3(2, (NN+127)/128), 256, 0, stream>>>(dout + layer*DH, NN, ac1, sums2);
        finalize_k<<<2, 256, 0, stream>>>(sums2, bn2_g[layer], bn2_b[layer], ac2);
        bn2write_k<<<((long)NN*DH + 255)/256, 256, 0, stream>>>(dout + layer*DH, ac2, hbf);
    }
}

// Round 19
// 865.397 us; speedup vs baseline: 1.2528x; 1.1000x over previous
//
#include <hip/hip_runtime.h>

#define NN   30000
#define NE   480000
#define NR   7
#define NSEG (NN*NR)
#define DH   512
#define DIN  21
#define EPSB 1e-5f
#define KSEG 3584          // 7*512 gathered columns (self handled from hbf)

typedef __attribute__((ext_vector_type(8))) short bf16x8;
typedef __attribute__((ext_vector_type(8))) unsigned short u16x8;
typedef __attribute__((ext_vector_type(4))) float f32x4;
typedef unsigned short ushortT;

static inline size_t align256(size_t x){ return (x + 255) & ~(size_t)255; }

__device__ inline float bf2f(ushortT u){
    unsigned int i = ((unsigned int)u) << 16; float f; __builtin_memcpy(&f, &i, 4); return f;
}
__device__ inline ushortT f2bf(float f){
    unsigned int i; __builtin_memcpy(&i, &f, 4);
    unsigned int r = i + 0x7FFFu + ((i >> 16) & 1u);
    return (ushortT)(r >> 16);
}

__device__ inline void load_lds16(const ushortT* g, ushortT* l){
    __builtin_amdgcn_global_load_lds((const __attribute__((address_space(1))) unsigned int*)g,
                                     (__attribute__((address_space(3))) unsigned int*)l,
                                     16, 0, 0);
}

// ---------------- CSR build (counting sort by seg = dst*7+rel) ----------------

__global__ void hist_k(const int* __restrict__ dst, const int* __restrict__ rel,
                       int* __restrict__ counts){
    int e = blockIdx.x*256 + threadIdx.x;
    if (e < NE) atomicAdd(&counts[dst[e]*NR + rel[e]], 1);
}

__global__ void scan1_k(const int* __restrict__ counts, int* __restrict__ bsum){
    __shared__ int sd[256];
    int t = threadIdx.x;
    int base = blockIdx.x*1024 + t*4;
    int s = 0;
#pragma unroll
    for (int i = 0; i < 4; i++){ int idx = base + i; if (idx < NSEG) s += counts[idx]; }
    sd[t] = s; __syncthreads();
    for (int off = 128; off > 0; off >>= 1){
        if (t < off) sd[t] += sd[t+off];
        __syncthreads();
    }
    if (t == 0) bsum[blockIdx.x] = sd[0];
}

__global__ void scan2_k(int* __restrict__ bsum, int nb, int* __restrict__ seg_start){
    __shared__ int sd[256];
    int t = threadIdx.x;
    int v = (t < nb) ? bsum[t] : 0;
    sd[t] = v; __syncthreads();
    for (int off = 1; off < 256; off <<= 1){
        int x = sd[t];
        if (t >= off) x += sd[t-off];
        __syncthreads();
        sd[t] = x; __syncthreads();
    }
    if (t < nb) bsum[t] = (t == 0) ? 0 : sd[t-1];
    if (t == 0) seg_start[NSEG] = NE;
}

__global__ void scan3_k(const int* __restrict__ counts, const int* __restrict__ bsum,
                        int* __restrict__ seg_start){
    __shared__ int sd[256];
    int t = threadIdx.x;
    int base = blockIdx.x*1024 + t*4;
    int v[4]; int s = 0;
#pragma unroll
    for (int i = 0; i < 4; i++){ int idx = base + i; v[i] = (idx < NSEG) ? counts[idx] : 0; s += v[i]; }
    sd[t] = s; __syncthreads();
    for (int off = 1; off < 256; off <<= 1){
        int x = sd[t];
        if (t >= off) x += sd[t-off];
        __syncthreads();
        sd[t] = x; __syncthreads();
    }
    int excl = sd[t] - s + bsum[blockIdx.x];
#pragma unroll
    for (int i = 0; i < 4; i++){
        int idx = base + i;
        if (idx < NSEG){ seg_start[idx] = excl; excl += v[i]; }
    }
}

__global__ void scatter_k(const int* __restrict__ src, const int* __restrict__ dst,
                          const int* __restrict__ rel, const int* __restrict__ seg_start,
                          int* __restrict__ cursor, int* __restrict__ src_sorted){
    int e = blockIdx.x*256 + threadIdx.x;
    if (e < NE){
        int s = dst[e]*NR + rel[e];
        int pos = seg_start[s] + atomicAdd(&cursor[s], 1);
        src_sorted[pos] = src[e];
    }
}

// ---------------- layer 0: segment sum d=21 → Acat0[*,256] (147 upd | 21 self | pad) --------

__global__ void segsum21b_k(const float* __restrict__ x0,
                            const int* __restrict__ seg_start, const int* __restrict__ src_sorted,
                            ushortT* __restrict__ Acat0){
    int n = blockIdx.x;
    int t = threadIdx.x;   // 64
    ushortT* arow = Acat0 + (long)n*256;
    if (t < DIN){
        int sb = n*NR;
        int e0 = seg_start[sb];
#pragma unroll
        for (int r = 0; r < NR; r++){
            int e1 = seg_start[sb + r + 1];
            float a = 0.f;
            for (int e = e0; e < e1; e++) a += x0[(long)src_sorted[e]*DIN + t];
            e0 = e1;
            arow[r*DIN + t] = f2bf(a);
        }
        arow[7*DIN + t] = f2bf(x0[(long)n*DIN + t]);
    }
    if (t >= 40) arow[168 + (t - 40)] = 0;   // 168..191
    arow[192 + t] = 0;                        // 192..255
}

// ---------------- segsum (layers 1,2): one WAVE per node → Acat[*,3584], grid-stride --------

__device__ inline void segsum_body(const ushortT* __restrict__ hbf,
                                   const int* __restrict__ seg_start,
                                   const int* __restrict__ src_sorted,
                                   ushortT* __restrict__ Acat,
                                   int wid, int c0, int lane){
    const int n = c0 + wid;
    const int co = lane*8;

    int sb[8];
#pragma unroll
    for (int i = 0; i < 8; i++) sb[i] = seg_start[n*NR + i];

    ushortT* arow = Acat + (long)wid*KSEG + co;
#pragma unroll
    for (int r = 0; r < NR; r++){
        float a[8];
#pragma unroll
        for (int j = 0; j < 8; j++) a[j] = 0.f;
        int e = sb[r], e1 = sb[r+1];
        for (; e + 3 < e1; e += 4){
            u16x8 v0 = *reinterpret_cast<const u16x8*>(hbf + (long)src_sorted[e  ]*DH + co);
            u16x8 v1 = *reinterpret_cast<const u16x8*>(hbf + (long)src_sorted[e+1]*DH + co);
            u16x8 v2 = *reinterpret_cast<const u16x8*>(hbf + (long)src_sorted[e+2]*DH + co);
            u16x8 v3 = *reinterpret_cast<const u16x8*>(hbf + (long)src_sorted[e+3]*DH + co);
#pragma unroll
            for (int j = 0; j < 8; j++)
                a[j] += (bf2f((ushortT)v0[j]) + bf2f((ushortT)v1[j]))
                      + (bf2f((ushortT)v2[j]) + bf2f((ushortT)v3[j]));
        }
        for (; e < e1; e++){
            u16x8 v = *reinterpret_cast<const u16x8*>(hbf + (long)src_sorted[e]*DH + co);
#pragma unroll
            for (int j = 0; j < 8; j++) a[j] += bf2f((ushortT)v[j]);
        }
        u16x8 o;
#pragma unroll
        for (int j = 0; j < 8; j++) o[j] = f2bf(a[j]);
        *reinterpret_cast<u16x8*>(arow + r*DH) = o;
    }
}

__global__ __launch_bounds__(256)
void segsum_wave_k(const ushortT* __restrict__ hbf,
                   const int* __restrict__ seg_start, const int* __restrict__ src_sorted,
                   ushortT* __restrict__ Acat, int c0, int cn){
    const int lane = threadIdx.x & 63;
    const int gwave = (blockIdx.x*256 + threadIdx.x) >> 6;
    const int nwaves = (gridDim.x*256) >> 6;
    for (int wid = gwave; wid < cn; wid += nwaves)
        segsum_body(hbf, seg_start, src_sorted, Acat, wid, c0, lane);
}

// ---------------- weight concat + bf16 convert: Wcat[512][Kp] ----------------

__global__ void convw_k(const float* __restrict__ lw, const float* __restrict__ sw,
                        int d, int Kp, ushortT* __restrict__ Wc){
    int i = blockIdx.x*256 + threadIdx.x;
    if (i < DH*Kp){
        int n = i / Kp, k = i % Kp;
        float v;
        if (k < 7*d)      v = lw[(long)n*7*d + k];
        else if (k < 8*d) v = sw[(long)n*d + (k - 7*d)];
        else              v = 0.f;
        Wc[i] = f2bf(v);
    }
}

// ---------------- 256x256 MFMA GEMM, 1 barrier per K-tile (staged-bytes-minimal) -----------
// 8 waves (2M x 4N of 128x64), BK=64, LDS = 2buf x (A[2half][128][64] + B[...]) = 128 KB.
// Staged bytes/layer = A x2 + W x(M/256) -- the R9-fit staging model says this is the wall.
// Per K-tile: {read ks0 frags (12), stage next tile A+B (8 loads), lgkm(0), 32 MFMA} then
// {read ks1 frags (12), lgkm(0), 32 MFMA}, vmcnt(0) (staged loads have ~full-iteration
// lead), ONE barrier. R15-verified fragment/staging geometry; T2 swizzle both sides.

__global__ __launch_bounds__(512)
void gemmX_k(const ushortT* __restrict__ A, int lda, int ntA,
             const ushortT* __restrict__ hbase, int M,
             const ushortT* __restrict__ W, int ldw,
             const float* __restrict__ b1, const float* __restrict__ b2,
             float* __restrict__ C, int ldc, int nt, float* __restrict__ sums){
    __shared__ ushortT As[2*2*128*64];   // [buf][half][128][64]
    __shared__ ushortT Bs[2*2*128*64];
    const int t = threadIdx.x;

    // bijective XCD swizzle; panel = l>>1, col-tile = l&1
    const int nwg = gridDim.x;
    int qq = nwg >> 3, rr = nwg & 7;
    int xcd = blockIdx.x & 7, slot = blockIdx.x >> 3;
    int l = xcd*qq + min(xcd, rr) + slot;
    const int bm = (l >> 1)*256;
    const int bn = (l & 1)*256;

    // staging constants (R15-verified): unit u0=t (rows 0-63 of half), u1=t+512 (rows 64-127)
    const int ur0 = t >> 3, ur1 = (t + 512) >> 3;
    const int sw0 = ((t & 7) ^ (ur0 & 7))*8;
    const int sw1 = ((t & 7) ^ (ur1 & 7))*8;
    const int a00 = min(bm + ur0, M-1),       a01 = min(bm + ur1, M-1);
    const int a10 = min(bm + 128 + ur0, M-1), a11 = min(bm + 128 + ur1, M-1);
    const int b00 = bn + ur0,       b01 = bn + ur1;
    const int b10 = bn + 128 + ur0, b11 = bn + 128 + ur1;

    auto stageA = [&](int kt, int h, int buf){
        ushortT* d = &As[(buf*2 + h)*8192];
        int r0 = h ? a10 : a00, r1 = h ? a11 : a01;
        const ushortT* p0;
        const ushortT* p1;
        if (kt < ntA){
            p0 = A + (long)r0*lda + kt*64 + sw0;
            p1 = A + (long)r1*lda + kt*64 + sw1;
        } else {
            int k0 = (kt - ntA)*64;
            p0 = hbase + (long)r0*DH + k0 + sw0;
            p1 = hbase + (long)r1*DH + k0 + sw1;
        }
        load_lds16(p0, d + t*8);
        load_lds16(p1, d + (t + 512)*8);
    };
    auto stageB = [&](int kt, int h, int buf){
        ushortT* d = &Bs[(buf*2 + h)*8192];
        int r0 = h ? b10 : b00, r1 = h ? b11 : b01;
        load_lds16(W + (long)r0*ldw + kt*64 + sw0, d + t*8);
        load_lds16(W + (long)r1*ldw + kt*64 + sw1, d + (t + 512)*8);
    };

    // fragment constants (R15-verified)
    const int w = t >> 6, lane = t & 63;
    const int wm = w >> 2, wn = w & 3;          // 2M x 4N, wave tile 128x64
    const int r = lane & 15, hi = lane >> 4;
    const int swzk0 = ((hi)     ^ (r & 7))*8;   // ks=0
    const int swzk1 = ((4 + hi) ^ (r & 7))*8;   // ks=1
    const int aBase = wm*8192 + r*64;
    const int bBase = (wn >> 1)*8192 + ((wn & 1)*64 + r)*64;

    f32x4 acc[8][4];
#pragma unroll
    for (int m = 0; m < 8; m++)
#pragma unroll
        for (int n = 0; n < 4; n++) acc[m][n] = (f32x4){0.f,0.f,0.f,0.f};

    // prologue: tile0 A+B -> buf0
    stageA(0, 0, 0); stageA(0, 1, 0);
    stageB(0, 0, 0); stageB(0, 1, 0);
    asm volatile("s_waitcnt vmcnt(0)" ::: "memory");
    __builtin_amdgcn_s_barrier();

    for (int j = 0; j < nt; ++j){
        const int buf = j & 1;
        const int aoff = buf*16384;
        const int boff = buf*16384;
        const bool haveNext = (j + 1 < nt);

        bf16x8 aK[8], bK[4];
        // ---- ks0 half-phase ----
#pragma unroll
        for (int m = 0; m < 8; m++)
            aK[m] = *reinterpret_cast<const bf16x8*>(&As[aoff + aBase + m*1024 + swzk0]);
#pragma unroll
        for (int n = 0; n < 4; n++)
            bK[n] = *reinterpret_cast<const bf16x8*>(&Bs[boff + bBase + n*1024 + swzk0]);
        if (haveNext){
            stageA(j + 1, 0, buf ^ 1); stageA(j + 1, 1, buf ^ 1);
            stageB(j + 1, 0, buf ^ 1); stageB(j + 1, 1, buf ^ 1);
        }
        asm volatile("s_waitcnt lgkmcnt(0)" ::: "memory");
        __builtin_amdgcn_sched_barrier(0);
        __builtin_amdgcn_s_setprio(1);
#pragma unroll
        for (int m = 0; m < 8; m++)
#pragma unroll
            for (int n = 0; n < 4; n++)
                acc[m][n] = __builtin_amdgcn_mfma_f32_16x16x32_bf16(aK[m], bK[n], acc[m][n], 0, 0, 0);
        __builtin_amdgcn_s_setprio(0);
        // ---- ks1 half-phase ----
#pragma unroll
        for (int m = 0; m < 8; m++)
            aK[m] = *reinterpret_cast<const bf16x8*>(&As[aoff + aBase + m*1024 + swzk1]);
#pragma unroll
        for (int n = 0; n < 4; n++)
            bK[n] = *reinterpret_cast<const bf16x8*>(&Bs[boff + bBase + n*1024 + swzk1]);
        asm volatile("s_waitcnt lgkmcnt(0)" ::: "memory");
        __builtin_amdgcn_sched_barrier(0);
        __builtin_amdgcn_s_setprio(1);
#pragma unroll
        for (int m = 0; m < 8; m++)
#pragma unroll
            for (int n = 0; n < 4; n++)
                acc[m][n] = __builtin_amdgcn_mfma_f32_16x16x32_bf16(aK[m], bK[n], acc[m][n], 0, 0, 0);
        __builtin_amdgcn_s_setprio(0);

        asm volatile("s_waitcnt vmcnt(0)" ::: "memory");   // next tile landed (~full iter lead)
        __builtin_amdgcn_s_barrier();
    }

    // epilogue: bias + fp32 store + fused column stats
#pragma unroll
    for (int n = 0; n < 4; n++){
        int col = bn + wn*64 + n*16 + r;
        float bb = b1[col] + b2[col];
        float s = 0.f, s2 = 0.f;
#pragma unroll
        for (int m = 0; m < 8; m++){
            int row = bm + wm*128 + m*16 + hi*4;
#pragma unroll
            for (int j2 = 0; j2 < 4; j2++){
                if (row + j2 < M){
                    float v = acc[m][n][j2] + bb;
                    C[(long)(row + j2)*ldc + col] = v;
                    s += v; s2 = fmaf(v, v, s2);
                }
            }
        }
        s  += __shfl_xor(s, 16);  s  += __shfl_xor(s, 32);
        s2 += __shfl_xor(s2, 16); s2 += __shfl_xor(s2, 32);
        if (hi == 0){
            atomicAdd(&sums[col], s);
            atomicAdd(&sums[DH + col], s2);
        }
    }
}

// ---------------- BatchNorm passes (fp32 in d_out) ----------------

__global__ void finalize_k(const float* __restrict__ sums, const float* __restrict__ g,
                           const float* __restrict__ b, float* __restrict__ ac){
    int c = blockIdx.x*256 + threadIdx.x;
    if (c < DH){
        float mu  = sums[c] * (1.f/NN);
        float var = sums[DH + c] * (1.f/NN) - mu*mu;
        var = fmaxf(var, 0.f);
        float a = g[c] * rsqrtf(var + EPSB);
        ac[c]      = a;
        ac[DH + c] = fmaf(-mu, a, b[c]);
    }
}

// read-only: stats of relu(a1*x+c1) — no intermediate write
__global__ void brstats_k(const float* __restrict__ o, int M, const float* __restrict__ ac,
                          float* __restrict__ sums2){
    int col = blockIdx.x*256 + threadIdx.x;
    int r0 = blockIdx.y*128;
    int r1 = min(r0 + 128, M);
    float a = ac[col], c = ac[DH + col];
    float s = 0.f, s2 = 0.f;
    for (int r = r0; r < r1; r++){
        float y = fmaxf(fmaf(a, o[(long)r*(3*DH) + col], c), 0.f);
        s += y; s2 = fmaf(y, y, s2);
    }
    atomicAdd(&sums2[col], s);
    atomicAdd(&sums2[DH + col], s2);
}

// single write pass: h = a2*relu(a1*x+c1)+c2 → o (and hbf when needed)
__global__ void bn2write_k(float* __restrict__ o, const float* __restrict__ ac1,
                           const float* __restrict__ ac2, ushortT* __restrict__ hbf,
                           int writeH){
    long i = (long)blockIdx.x*256 + threadIdx.x;
    if (i < (long)NN*DH){
        int r = (int)(i >> 9);
        int c = (int)(i & 511);
        long idx = (long)r*(3*DH) + c;
        float y = fmaxf(fmaf(ac1[c], o[idx], ac1[DH + c]), 0.f);
        float h = fmaf(ac2[c], y, ac2[DH + c]);
        o[idx] = h;
        if (writeH) hbf[i] = f2bf(h);
    }
}

// ---------------- driver ----------------

extern "C" void kernel_launch(void* const* d_in, const int* in_sizes, int n_in,
                              void* d_out, int out_size, void* d_ws, size_t ws_size,
                              hipStream_t stream){
    const float* x0  = (const float*)d_in[0];
    const int*   src = (const int*)d_in[1];
    const int*   dst = (const int*)d_in[2];
    const int*   rel = (const int*)d_in[3];
    const float* lin_w[3]  = {(const float*)d_in[4],  (const float*)d_in[12], (const float*)d_in[20]};
    const float* self_w[3] = {(const float*)d_in[5],  (const float*)d_in[13], (const float*)d_in[21]};
    const float* lin_b[3]  = {(const float*)d_in[6],  (const float*)d_in[14], (const float*)d_in[22]};
    const float* self_b[3] = {(const float*)d_in[7],  (const float*)d_in[15], (const float*)d_in[23]};
    const float* bn1_g[3]  = {(const float*)d_in[8],  (const float*)d_in[16], (const float*)d_in[24]};
    const float* bn1_b[3]  = {(const float*)d_in[9],  (const float*)d_in[17], (const float*)d_in[25]};
    const float* bn2_g[3]  = {(const float*)d_in[10], (const float*)d_in[18], (const float*)d_in[26]};
    const float* bn2_b[3]  = {(const float*)d_in[11], (const float*)d_in[19], (const float*)d_in[27]};

    char* ws = (char*)d_ws;
    size_t off = 0;
    auto alloc = [&](size_t bytes)->char*{ char* p = ws + off; off = align256(off + bytes); return p; };

    int*     seg_start  = (int*)alloc((size_t)(NSEG+1)*4);
    int*     bsum       = (int*)alloc(1024*4);
    int*     src_sorted = (int*)alloc((size_t)NE*4);
    float*   stats      = (float*)alloc((size_t)8*DH*4);
    float*   sums1 = stats;            float* sums2 = stats + 2*DH;
    float*   ac1   = stats + 4*DH;     float* ac2   = stats + 6*DH;
    ushortT* hbf    = (ushortT*)alloc((size_t)NN*DH*2);
    ushortT* Wcat   = (ushortT*)alloc((size_t)DH*4096*2);

    // Acat takes the remainder. counts/cursor (CSR) and Acat0 (layer 0) are aliased
    // into the Acat region — all dead before the first layer-1 segsum write (stream-serial).
    size_t remain = (ws_size > off) ? (ws_size - off) : 0;
    ushortT* Acat   = (ushortT*)(ws + off);
    int*     counts = (int*)Acat;
    int*     cursor = counts + NSEG;
    ushortT* Acat0  = (ushortT*)align256((size_t)(cursor + NSEG));

    long max_nodes = (long)(remain / ((size_t)KSEG*2));
    int chunk;
    if (max_nodes >= NN) chunk = NN;
    else { chunk = (int)(max_nodes & ~255L); if (chunk < 2560) chunk = 2560; }

    // CSR build (graph is layer-invariant)
    hipMemsetAsync(counts, 0, (size_t)NSEG*4, stream);
    hipMemsetAsync(cursor, 0, (size_t)NSEG*4, stream);
    hist_k<<<(NE+255)/256, 256, 0, stream>>>(dst, rel, counts);
    int nb = (NSEG + 1023)/1024;
    scan1_k<<<nb, 256, 0, stream>>>(counts, bsum);
    scan2_k<<<1, 256, 0, stream>>>(bsum, nb, seg_start);
    scan3_k<<<nb, 256, 0, stream>>>(counts, bsum, seg_start);
    scatter_k<<<(NE+255)/256, 256, 0, stream>>>(src, dst, rel, seg_start, cursor, src_sorted);

    float* dout = (float*)d_out;

    for (int layer = 0; layer < 3; layer++){
        int d  = (layer == 0) ? DIN : DH;
        int Kp = (layer == 0) ? 256 : 4096;
        convw_k<<<(DH*Kp + 255)/256, 256, 0, stream>>>(lin_w[layer], self_w[layer], d, Kp, Wcat);
        hipMemsetAsync(stats, 0, (size_t)4*DH*4, stream);   // sums1 + sums2

        if (layer == 0){
            segsum21b_k<<<NN, 64, 0, stream>>>(x0, seg_start, src_sorted, Acat0);
            gemmX_k<<<((NN + 255)/256)*2, 512, 0, stream>>>(
                Acat0, 256, 4, Acat0, NN, Wcat, 256,
                lin_b[layer], self_b[layer],
                dout + layer*DH, 3*DH, 4, sums1);
        } else {
            for (int c0 = 0; c0 < NN; c0 += chunk){
                int cn = (NN - c0 < chunk) ? (NN - c0) : chunk;
                int sgrid = (cn + 3)/4; if (sgrid > 2048) sgrid = 2048;
                segsum_wave_k<<<sgrid, 256, 0, stream>>>(
                    hbf, seg_start, src_sorted, Acat, c0, cn);
                gemmX_k<<<((cn + 255)/256)*2, 512, 0, stream>>>(
                    Acat, KSEG, 56, hbf + (long)c0*DH, cn, Wcat, 4096,
                    lin_b[layer], self_b[layer],
                    dout + (long)c0*(3*DH) + layer*DH, 3*DH, 64, sums1);
            }
        }

        finalize_k<<<2, 256, 0, stream>>>(sums1, bn1_g[layer], bn1_b[layer], ac1);
        brstats_k<<<dim3(2, (NN+127)/128), 256, 0, stream>>>(dout + layer*DH, NN, ac1, sums2);
        finalize_k<<<2, 256, 0, stream>>>(sums2, bn2_g[layer], bn2_b[layer], ac2);
        bn2write_k<<<((long)NN*DH + 255)/256, 256, 0, stream>>>(
            dout + layer*DH, ac1, ac2, hbf, (layer < 2) ? 1 : 0);
    }
}

// Round 20
// 857.765 us; speedup vs baseline: 1.2640x; 1.0089x over previous
//
#include <hip/hip_runtime.h>

#define NN   30000
#define NE   480000
#define NR   7
#define NSEG (NN*NR)
#define DH   512
#define DIN  21
#define EPSB 1e-5f
#define KSEG 3584          // 7*512 gathered columns (self handled from hbf)

typedef __attribute__((ext_vector_type(8))) short bf16x8;
typedef __attribute__((ext_vector_type(8))) unsigned short u16x8;
typedef __attribute__((ext_vector_type(4))) float f32x4;
typedef unsigned short ushortT;

static inline size_t align256(size_t x){ return (x + 255) & ~(size_t)255; }

__device__ inline float bf2f(ushortT u){
    unsigned int i = ((unsigned int)u) << 16; float f; __builtin_memcpy(&f, &i, 4); return f;
}
__device__ inline ushortT f2bf(float f){
    unsigned int i; __builtin_memcpy(&i, &f, 4);
    unsigned int r = i + 0x7FFFu + ((i >> 16) & 1u);
    return (ushortT)(r >> 16);
}

__device__ inline void load_lds16(const ushortT* g, ushortT* l){
    __builtin_amdgcn_global_load_lds((const __attribute__((address_space(1))) unsigned int*)g,
                                     (__attribute__((address_space(3))) unsigned int*)l,
                                     16, 0, 0);
}

// ---------------- CSR build (counting sort by seg = dst*7+rel) ----------------

__global__ void hist_k(const int* __restrict__ dst, const int* __restrict__ rel,
                       int* __restrict__ counts){
    int e = blockIdx.x*256 + threadIdx.x;
    if (e < NE) atomicAdd(&counts[dst[e]*NR + rel[e]], 1);
}

__global__ void scan1_k(const int* __restrict__ counts, int* __restrict__ bsum){
    __shared__ int sd[256];
    int t = threadIdx.x;
    int base = blockIdx.x*1024 + t*4;
    int s = 0;
#pragma unroll
    for (int i = 0; i < 4; i++){ int idx = base + i; if (idx < NSEG) s += counts[idx]; }
    sd[t] = s; __syncthreads();
    for (int off = 128; off > 0; off >>= 1){
        if (t < off) sd[t] += sd[t+off];
        __syncthreads();
    }
    if (t == 0) bsum[blockIdx.x] = sd[0];
}

__global__ void scan2_k(int* __restrict__ bsum, int nb, int* __restrict__ seg_start){
    __shared__ int sd[256];
    int t = threadIdx.x;
    int v = (t < nb) ? bsum[t] : 0;
    sd[t] = v; __syncthreads();
    for (int off = 1; off < 256; off <<= 1){
        int x = sd[t];
        if (t >= off) x += sd[t-off];
        __syncthreads();
        sd[t] = x; __syncthreads();
    }
    if (t < nb) bsum[t] = (t == 0) ? 0 : sd[t-1];
    if (t == 0) seg_start[NSEG] = NE;
}

__global__ void scan3_k(const int* __restrict__ counts, const int* __restrict__ bsum,
                        int* __restrict__ seg_start){
    __shared__ int sd[256];
    int t = threadIdx.x;
    int base = blockIdx.x*1024 + t*4;
    int v[4]; int s = 0;
#pragma unroll
    for (int i = 0; i < 4; i++){ int idx = base + i; v[i] = (idx < NSEG) ? counts[idx] : 0; s += v[i]; }
    sd[t] = s; __syncthreads();
    for (int off = 1; off < 256; off <<= 1){
        int x = sd[t];
        if (t >= off) x += sd[t-off];
        __syncthreads();
        sd[t] = x; __syncthreads();
    }
    int excl = sd[t] - s + bsum[blockIdx.x];
#pragma unroll
    for (int i = 0; i < 4; i++){
        int idx = base + i;
        if (idx < NSEG){ seg_start[idx] = excl; excl += v[i]; }
    }
}

__global__ void scatter_k(const int* __restrict__ src, const int* __restrict__ dst,
                          const int* __restrict__ rel, const int* __restrict__ seg_start,
                          int* __restrict__ cursor, int* __restrict__ src_sorted){
    int e = blockIdx.x*256 + threadIdx.x;
    if (e < NE){
        int s = dst[e]*NR + rel[e];
        int pos = seg_start[s] + atomicAdd(&cursor[s], 1);
        src_sorted[pos] = src[e];
    }
}

// ---------------- layer 0: segment sum d=21 → Acat0[*,256] (147 upd | 21 self | pad) --------

__global__ void segsum21b_k(const float* __restrict__ x0,
                            const int* __restrict__ seg_start, const int* __restrict__ src_sorted,
                            ushortT* __restrict__ Acat0){
    int n = blockIdx.x;
    int t = threadIdx.x;   // 64
    ushortT* arow = Acat0 + (long)n*256;
    if (t < DIN){
        int sb = n*NR;
        int e0 = seg_start[sb];
#pragma unroll
        for (int r = 0; r < NR; r++){
            int e1 = seg_start[sb + r + 1];
            float a = 0.f;
            for (int e = e0; e < e1; e++) a += x0[(long)src_sorted[e]*DIN + t];
            e0 = e1;
            arow[r*DIN + t] = f2bf(a);
        }
        arow[7*DIN + t] = f2bf(x0[(long)n*DIN + t]);
    }
    if (t >= 40) arow[168 + (t - 40)] = 0;   // 168..191
    arow[192 + t] = 0;                        // 192..255
}

// ---------------- segsum (layers 1,2): one WAVE per node → Acat[*,3584], grid-stride --------

__device__ inline void segsum_body(const ushortT* __restrict__ hbf,
                                   const int* __restrict__ seg_start,
                                   const int* __restrict__ src_sorted,
                                   ushortT* __restrict__ Acat,
                                   int wid, int c0, int lane){
    const int n = c0 + wid;
    const int co = lane*8;

    int sb[8];
#pragma unroll
    for (int i = 0; i < 8; i++) sb[i] = seg_start[n*NR + i];

    ushortT* arow = Acat + (long)wid*KSEG + co;
#pragma unroll
    for (int r = 0; r < NR; r++){
        float a[8];
#pragma unroll
        for (int j = 0; j < 8; j++) a[j] = 0.f;
        int e = sb[r], e1 = sb[r+1];
        for (; e + 3 < e1; e += 4){
            u16x8 v0 = *reinterpret_cast<const u16x8*>(hbf + (long)src_sorted[e  ]*DH + co);
            u16x8 v1 = *reinterpret_cast<const u16x8*>(hbf + (long)src_sorted[e+1]*DH + co);
            u16x8 v2 = *reinterpret_cast<const u16x8*>(hbf + (long)src_sorted[e+2]*DH + co);
            u16x8 v3 = *reinterpret_cast<const u16x8*>(hbf + (long)src_sorted[e+3]*DH + co);
#pragma unroll
            for (int j = 0; j < 8; j++)
                a[j] += (bf2f((ushortT)v0[j]) + bf2f((ushortT)v1[j]))
                      + (bf2f((ushortT)v2[j]) + bf2f((ushortT)v3[j]));
        }
        for (; e < e1; e++){
            u16x8 v = *reinterpret_cast<const u16x8*>(hbf + (long)src_sorted[e]*DH + co);
#pragma unroll
            for (int j = 0; j < 8; j++) a[j] += bf2f((ushortT)v[j]);
        }
        u16x8 o;
#pragma unroll
        for (int j = 0; j < 8; j++) o[j] = f2bf(a[j]);
        *reinterpret_cast<u16x8*>(arow + r*DH) = o;
    }
}

__global__ __launch_bounds__(256)
void segsum_wave_k(const ushortT* __restrict__ hbf,
                   const int* __restrict__ seg_start, const int* __restrict__ src_sorted,
                   ushortT* __restrict__ Acat, int c0, int cn){
    const int lane = threadIdx.x & 63;
    const int gwave = (blockIdx.x*256 + threadIdx.x) >> 6;
    const int nwaves = (gridDim.x*256) >> 6;
    for (int wid = gwave; wid < cn; wid += nwaves)
        segsum_body(hbf, seg_start, src_sorted, Acat, wid, c0, lane);
}

// ---------------- weight concat + bf16 convert: Wcat[512][Kp] ----------------

__global__ void convw_k(const float* __restrict__ lw, const float* __restrict__ sw,
                        int d, int Kp, ushortT* __restrict__ Wc){
    int i = blockIdx.x*256 + threadIdx.x;
    if (i < DH*Kp){
        int n = i / Kp, k = i % Kp;
        float v;
        if (k < 7*d)      v = lw[(long)n*7*d + k];
        else if (k < 8*d) v = sw[(long)n*d + (k - 7*d)];
        else              v = 0.f;
        Wc[i] = f2bf(v);
    }
}

// ---------------- 256x256 MFMA GEMM, A 3-buf + counted vmcnt(4) ----------------
// 8 waves (2M x 4N of 128x64), BK=64. LDS = A 3-buf (96 KB) + B 2-buf (64 KB) = 160 KB
// (full CU LDS — launchable on gfx950, cf. AITER fmha 160KB workgroups).
// Per K-tile j: read ks0 frags, stage B(j+1)->bbuf^1 + A(j+2)->(j+2)%3 (8 loads),
// lgkm(0)+32 MFMA, ks1 half-phase, then vmcnt(4): A(j+2)'s 4 loads stay in flight across
// the barrier (A gets ~2 iterations of lead; older A(j+1)/B(j+1) transitively landed).
// R19-verified fragment/staging geometry + T2 swizzle. fp32 C into d_out, fused col-stats.

__global__ __launch_bounds__(512)
void gemmY_k(const ushortT* __restrict__ A, int lda, int ntA,
             const ushortT* __restrict__ hbase, int M,
             const ushortT* __restrict__ W, int ldw,
             const float* __restrict__ b1, const float* __restrict__ b2,
             float* __restrict__ C, int ldc, int nt, float* __restrict__ sums){
    __shared__ ushortT As[3*2*128*64];   // 96 KB: [abuf][half][128][64]
    __shared__ ushortT Bs[2*2*128*64];   // 64 KB: [bbuf][half][128][64]
    const int t = threadIdx.x;

    // bijective XCD swizzle; panel = l>>1, col-tile = l&1
    const int nwg = gridDim.x;
    int qq = nwg >> 3, rr = nwg & 7;
    int xcd = blockIdx.x & 7, slot = blockIdx.x >> 3;
    int l = xcd*qq + min(xcd, rr) + slot;
    const int bm = (l >> 1)*256;
    const int bn = (l & 1)*256;

    // staging constants: unit u0=t (rows 0-63 of half), u1=t+512 (rows 64-127)
    const int ur0 = t >> 3, ur1 = (t + 512) >> 3;
    const int sw0 = ((t & 7) ^ (ur0 & 7))*8;
    const int sw1 = ((t & 7) ^ (ur1 & 7))*8;
    const int a00 = min(bm + ur0, M-1),       a01 = min(bm + ur1, M-1);
    const int a10 = min(bm + 128 + ur0, M-1), a11 = min(bm + 128 + ur1, M-1);
    const int b00 = bn + ur0,       b01 = bn + ur1;
    const int b10 = bn + 128 + ur0, b11 = bn + 128 + ur1;

    auto stageA = [&](int kt, int h, int buf){
        ushortT* d = &As[buf*16384 + h*8192];
        int r0 = h ? a10 : a00, r1 = h ? a11 : a01;
        const ushortT* p0;
        const ushortT* p1;
        if (kt < ntA){
            p0 = A + (long)r0*lda + kt*64 + sw0;
            p1 = A + (long)r1*lda + kt*64 + sw1;
        } else {
            int k0 = (kt - ntA)*64;
            p0 = hbase + (long)r0*DH + k0 + sw0;
            p1 = hbase + (long)r1*DH + k0 + sw1;
        }
        load_lds16(p0, d + t*8);
        load_lds16(p1, d + (t + 512)*8);
    };
    auto stageB = [&](int kt, int h, int buf){
        ushortT* d = &Bs[buf*16384 + h*8192];
        int r0 = h ? b10 : b00, r1 = h ? b11 : b01;
        load_lds16(W + (long)r0*ldw + kt*64 + sw0, d + t*8);
        load_lds16(W + (long)r1*ldw + kt*64 + sw1, d + (t + 512)*8);
    };

    // fragment constants (R19-verified)
    const int w = t >> 6, lane = t & 63;
    const int wm = w >> 2, wn = w & 3;          // 2M x 4N, wave tile 128x64
    const int r = lane & 15, hi = lane >> 4;
    const int swzk0 = ((hi)     ^ (r & 7))*8;   // ks=0
    const int swzk1 = ((4 + hi) ^ (r & 7))*8;   // ks=1
    const int aBase = wm*8192 + r*64;                          // + abuf*16384
    const int bBase = (wn >> 1)*8192 + ((wn & 1)*64 + r)*64;   // + bbuf*16384

    f32x4 acc[8][4];
#pragma unroll
    for (int m = 0; m < 8; m++)
#pragma unroll
        for (int n = 0; n < 4; n++) acc[m][n] = (f32x4){0.f,0.f,0.f,0.f};

    // prologue: A(0)->abuf0, B(0)->bbuf0, A(1)->abuf1; keep A(1)'s 4 loads in flight
    stageA(0, 0, 0); stageA(0, 1, 0);
    stageB(0, 0, 0); stageB(0, 1, 0);
    if (nt > 1){ stageA(1, 0, 1); stageA(1, 1, 1); }
    asm volatile("s_waitcnt vmcnt(4)" ::: "memory");
    __builtin_amdgcn_s_barrier();

    for (int j = 0; j < nt; ++j){
        const int aoff = (j % 3)*16384;
        const int boff = (j & 1)*16384;
        const bool haveB = (j + 1 < nt);
        const bool haveA = (j + 2 < nt);

        bf16x8 aK[8], bK[4];
        // ---- ks0 half-phase ----
#pragma unroll
        for (int m = 0; m < 8; m++)
            aK[m] = *reinterpret_cast<const bf16x8*>(&As[aoff + aBase + m*1024 + swzk0]);
#pragma unroll
        for (int n = 0; n < 4; n++)
            bK[n] = *reinterpret_cast<const bf16x8*>(&Bs[boff + bBase + n*1024 + swzk0]);
        if (haveB){ stageB(j + 1, 0, (j + 1) & 1); stageB(j + 1, 1, (j + 1) & 1); }
        if (haveA){ stageA(j + 2, 0, (j + 2) % 3); stageA(j + 2, 1, (j + 2) % 3); }
        asm volatile("s_waitcnt lgkmcnt(0)" ::: "memory");
        __builtin_amdgcn_sched_barrier(0);
        __builtin_amdgcn_s_setprio(1);
#pragma unroll
        for (int m = 0; m < 8; m++)
#pragma unroll
            for (int n = 0; n < 4; n++)
                acc[m][n] = __builtin_amdgcn_mfma_f32_16x16x32_bf16(aK[m], bK[n], acc[m][n], 0, 0, 0);
        __builtin_amdgcn_s_setprio(0);
        // ---- ks1 half-phase ----
#pragma unroll
        for (int m = 0; m < 8; m++)
            aK[m] = *reinterpret_cast<const bf16x8*>(&As[aoff + aBase + m*1024 + swzk1]);
#pragma unroll
        for (int n = 0; n < 4; n++)
            bK[n] = *reinterpret_cast<const bf16x8*>(&Bs[boff + bBase + n*1024 + swzk1]);
        asm volatile("s_waitcnt lgkmcnt(0)" ::: "memory");
        __builtin_amdgcn_sched_barrier(0);
        __builtin_amdgcn_s_setprio(1);
#pragma unroll
        for (int m = 0; m < 8; m++)
#pragma unroll
            for (int n = 0; n < 4; n++)
                acc[m][n] = __builtin_amdgcn_mfma_f32_16x16x32_bf16(aK[m], bK[n], acc[m][n], 0, 0, 0);
        __builtin_amdgcn_s_setprio(0);

        // guard: B(j+1) (and transitively A(j+1)) landed; A(j+2)'s 4 loads stay in flight
        if (haveA) asm volatile("s_waitcnt vmcnt(4)" ::: "memory");
        else       asm volatile("s_waitcnt vmcnt(0)" ::: "memory");
        __builtin_amdgcn_s_barrier();
    }

    // epilogue: bias + fp32 store + fused column stats
#pragma unroll
    for (int n = 0; n < 4; n++){
        int col = bn + wn*64 + n*16 + r;
        float bb = b1[col] + b2[col];
        float s = 0.f, s2 = 0.f;
#pragma unroll
        for (int m = 0; m < 8; m++){
            int row = bm + wm*128 + m*16 + hi*4;
#pragma unroll
            for (int j2 = 0; j2 < 4; j2++){
                if (row + j2 < M){
                    float v = acc[m][n][j2] + bb;
                    C[(long)(row + j2)*ldc + col] = v;
                    s += v; s2 = fmaf(v, v, s2);
                }
            }
        }
        s  += __shfl_xor(s, 16);  s  += __shfl_xor(s, 32);
        s2 += __shfl_xor(s2, 16); s2 += __shfl_xor(s2, 32);
        if (hi == 0){
            atomicAdd(&sums[col], s);
            atomicAdd(&sums[DH + col], s2);
        }
    }
}

// ---------------- BatchNorm passes (fp32 in d_out) ----------------

__global__ void finalize_k(const float* __restrict__ sums, const float* __restrict__ g,
                           const float* __restrict__ b, float* __restrict__ ac){
    int c = blockIdx.x*256 + threadIdx.x;
    if (c < DH){
        float mu  = sums[c] * (1.f/NN);
        float var = sums[DH + c] * (1.f/NN) - mu*mu;
        var = fmaxf(var, 0.f);
        float a = g[c] * rsqrtf(var + EPSB);
        ac[c]      = a;
        ac[DH + c] = fmaf(-mu, a, b[c]);
    }
}

// read-only: stats of relu(a1*x+c1) — no intermediate write
__global__ void brstats_k(const float* __restrict__ o, int M, const float* __restrict__ ac,
                          float* __restrict__ sums2){
    int col = blockIdx.x*256 + threadIdx.x;
    int r0 = blockIdx.y*128;
    int r1 = min(r0 + 128, M);
    float a = ac[col], c = ac[DH + col];
    float s = 0.f, s2 = 0.f;
    for (int r = r0; r < r1; r++){
        float y = fmaxf(fmaf(a, o[(long)r*(3*DH) + col], c), 0.f);
        s += y; s2 = fmaf(y, y, s2);
    }
    atomicAdd(&sums2[col], s);
    atomicAdd(&sums2[DH + col], s2);
}

// single write pass: h = a2*relu(a1*x+c1)+c2 → o (and hbf when needed)
__global__ void bn2write_k(float* __restrict__ o, const float* __restrict__ ac1,
                           const float* __restrict__ ac2, ushortT* __restrict__ hbf,
                           int writeH){
    long i = (long)blockIdx.x*256 + threadIdx.x;
    if (i < (long)NN*DH){
        int r = (int)(i >> 9);
        int c = (int)(i & 511);
        long idx = (long)r*(3*DH) + c;
        float y = fmaxf(fmaf(ac1[c], o[idx], ac1[DH + c]), 0.f);
        float h = fmaf(ac2[c], y, ac2[DH + c]);
        o[idx] = h;
        if (writeH) hbf[i] = f2bf(h);
    }
}

// ---------------- driver ----------------

extern "C" void kernel_launch(void* const* d_in, const int* in_sizes, int n_in,
                              void* d_out, int out_size, void* d_ws, size_t ws_size,
                              hipStream_t stream){
    const float* x0  = (const float*)d_in[0];
    const int*   src = (const int*)d_in[1];
    const int*   dst = (const int*)d_in[2];
    const int*   rel = (const int*)d_in[3];
    const float* lin_w[3]  = {(const float*)d_in[4],  (const float*)d_in[12], (const float*)d_in[20]};
    const float* self_w[3] = {(const float*)d_in[5],  (const float*)d_in[13], (const float*)d_in[21]};
    const float* lin_b[3]  = {(const float*)d_in[6],  (const float*)d_in[14], (const float*)d_in[22]};
    const float* self_b[3] = {(const float*)d_in[7],  (const float*)d_in[15], (const float*)d_in[23]};
    const float* bn1_g[3]  = {(const float*)d_in[8],  (const float*)d_in[16], (const float*)d_in[24]};
    const float* bn1_b[3]  = {(const float*)d_in[9],  (const float*)d_in[17], (const float*)d_in[25]};
    const float* bn2_g[3]  = {(const float*)d_in[10], (const float*)d_in[18], (const float*)d_in[26]};
    const float* bn2_b[3]  = {(const float*)d_in[11], (const float*)d_in[19], (const float*)d_in[27]};

    char* ws = (char*)d_ws;
    size_t off = 0;
    auto alloc = [&](size_t bytes)->char*{ char* p = ws + off; off = align256(off + bytes); return p; };

    int*     seg_start  = (int*)alloc((size_t)(NSEG+1)*4);
    int*     bsum       = (int*)alloc(1024*4);
    int*     src_sorted = (int*)alloc((size_t)NE*4);
    float*   stats      = (float*)alloc((size_t)8*DH*4);
    float*   sums1 = stats;            float* sums2 = stats + 2*DH;
    float*   ac1   = stats + 4*DH;     float* ac2   = stats + 6*DH;
    ushortT* hbf    = (ushortT*)alloc((size_t)NN*DH*2);
    ushortT* Wcat   = (ushortT*)alloc((size_t)DH*4096*2);

    // Acat takes the remainder. counts/cursor (CSR) and Acat0 (layer 0) are aliased
    // into the Acat region — all dead before the first layer-1 segsum write (stream-serial).
    size_t remain = (ws_size > off) ? (ws_size - off) : 0;
    ushortT* Acat   = (ushortT*)(ws + off);
    int*     counts = (int*)Acat;
    int*     cursor = counts + NSEG;
    ushortT* Acat0  = (ushortT*)align256((size_t)(cursor + NSEG));

    long max_nodes = (long)(remain / ((size_t)KSEG*2));
    int chunk;
    if (max_nodes >= NN) chunk = NN;
    else { chunk = (int)(max_nodes & ~255L); if (chunk < 2560) chunk = 2560; }

    // CSR build (graph is layer-invariant)
    hipMemsetAsync(counts, 0, (size_t)NSEG*4, stream);
    hipMemsetAsync(cursor, 0, (size_t)NSEG*4, stream);
    hist_k<<<(NE+255)/256, 256, 0, stream>>>(dst, rel, counts);
    int nb = (NSEG + 1023)/1024;
    scan1_k<<<nb, 256, 0, stream>>>(counts, bsum);
    scan2_k<<<1, 256, 0, stream>>>(bsum, nb, seg_start);
    scan3_k<<<nb, 256, 0, stream>>>(counts, bsum, seg_start);
    scatter_k<<<(NE+255)/256, 256, 0, stream>>>(src, dst, rel, seg_start, cursor, src_sorted);

    float* dout = (float*)d_out;

    for (int layer = 0; layer < 3; layer++){
        int d  = (layer == 0) ? DIN : DH;
        int Kp = (layer == 0) ? 256 : 4096;
        convw_k<<<(DH*Kp + 255)/256, 256, 0, stream>>>(lin_w[layer], self_w[layer], d, Kp, Wcat);
        hipMemsetAsync(stats, 0, (size_t)4*DH*4, stream);   // sums1 + sums2

        if (layer == 0){
            segsum21b_k<<<NN, 64, 0, stream>>>(x0, seg_start, src_sorted, Acat0);
            gemmY_k<<<((NN + 255)/256)*2, 512, 0, stream>>>(
                Acat0, 256, 4, Acat0, NN, Wcat, 256,
                lin_b[layer], self_b[layer],
                dout + layer*DH, 3*DH, 4, sums1);
        } else {
            for (int c0 = 0; c0 < NN; c0 += chunk){
                int cn = (NN - c0 < chunk) ? (NN - c0) : chunk;
                int sgrid = (cn + 3)/4; if (sgrid > 2048) sgrid = 2048;
                segsum_wave_k<<<sgrid, 256, 0, stream>>>(
                    hbf, seg_start, src_sorted, Acat, c0, cn);
                gemmY_k<<<((cn + 255)/256)*2, 512, 0, stream>>>(
                    Acat, KSEG, 56, hbf + (long)c0*DH, cn, Wcat, 4096,
                    lin_b[layer], self_b[layer],
                    dout + (long)c0*(3*DH) + layer*DH, 3*DH, 64, sums1);
            }
        }

        finalize_k<<<2, 256, 0, stream>>>(sums1, bn1_g[layer], bn1_b[layer], ac1);
        brstats_k<<<dim3(2, (NN+127)/128), 256, 0, stream>>>(dout + layer*DH, NN, ac1, sums2);
        finalize_k<<<2, 256, 0, stream>>>(sums2, bn2_g[layer], bn2_b[layer], ac2);
        bn2write_k<<<((long)NN*DH + 255)/256, 256, 0, stream>>>(
            dout + layer*DH, ac1, ac2, hbf, (layer < 2) ? 1 : 0);
    }
}